// Round 18
// baseline (267.177 us; speedup 1.0000x reference)
//
#include <hip/hip_runtime.h>
#include <hip/hip_fp16.h>
#include <stdint.h>

typedef __attribute__((ext_vector_type(4))) float f32x4;
typedef __attribute__((ext_vector_type(2))) float f32x2;
typedef _Float16 f16;
typedef __attribute__((ext_vector_type(8))) _Float16 f16x8;
typedef __attribute__((ext_vector_type(4))) _Float16 f16x4;

#define LN_EPS 1e-5f

// ---------------- helpers ----------------
__device__ __forceinline__ void gload_lds16(const void* g, void* l) {
  __builtin_amdgcn_global_load_lds(
      (__attribute__((address_space(1))) void*)(uintptr_t)g,
      (__attribute__((address_space(3))) void*)(uint32_t)(uintptr_t)l,
      16, 0, 0);
}

__device__ __forceinline__ f32x4 mfma16(f16x8 a, f16x8 b, f32x4 c) {
  return __builtin_amdgcn_mfma_f32_16x16x32_f16(a, b, c, 0, 0, 0);
}

// read 8-wide per-row (s,sq) partials and form LN scale/shift
__device__ __forceinline__ void ln_coeff(const f32x2* __restrict__ inPart, int r,
                                         float* rstd_o, float* shift_o) {
  const f32x4* pp = (const f32x4*)(inPart + (size_t)r * 8);
  f32x4 p0 = pp[0], p1 = pp[1], p2 = pp[2], p3 = pp[3];
  float s = p0[0] + p0[2] + p1[0] + p1[2] + p2[0] + p2[2] + p3[0] + p3[2];
  float q = p0[1] + p0[3] + p1[1] + p1[3] + p2[1] + p2[3] + p3[1] + p3[3];
  float mu = s * (1.0f / 1024.0f);
  float var = q * (1.0f / 1024.0f) - mu * mu;
  float rstd = rsqrtf(var + LN_EPS);
  *rstd_o = rstd;
  *shift_o = -mu * rstd;
}

// ---------------- prep megakernel (weights + logE) ----------------
__device__ __forceinline__ void transpose256(const float* __restrict__ W,
                                             f16* __restrict__ Wt, int K, int N,
                                             int nt, int kt, float (*t)[33]) {
  int tx = threadIdx.x & 31;
  int ty0 = (threadIdx.x >> 5) * 4;
#pragma unroll
  for (int j = 0; j < 4; ++j)
    t[ty0 + j][tx] = W[(size_t)(kt + ty0 + j) * N + nt + tx];
  __syncthreads();
#pragma unroll
  for (int j = 0; j < 4; ++j)
    Wt[(size_t)(nt + ty0 + j) * K + kt + tx] = (f16)t[tx][ty0 + j];
}

__global__ __launch_bounds__(256) void k_prep(
    const float* __restrict__ W1, f16* __restrict__ W1t,
    const float* __restrict__ W2, f16* __restrict__ W2t,
    const float* __restrict__ W3, f16* __restrict__ W3t,
    const float* __restrict__ W4, f16* __restrict__ W4t,
    const float* __restrict__ W5, f16* __restrict__ W5t,
    const float* __restrict__ emb, f16* __restrict__ logE) {
  __shared__ float t[32][33];
  const int b = blockIdx.x;
  if (b < 512) {
    transpose256(W1, W1t, 512, 1024, (b & 31) * 32, (b >> 5) * 32, t);
  } else if (b < 3584) {
    int b3 = b - 512;
    int z = b3 >> 10;
    int b4 = b3 & 1023;
    const float* W = z == 0 ? W2 : (z == 1 ? W3 : W4);
    f16* T = z == 0 ? W2t : (z == 1 ? W3t : W4t);
    transpose256(W, T, 1024, 1024, (b4 & 31) * 32, (b4 >> 5) * 32, t);
  } else if (b < 3840) {
    int b5 = b - 3584;
    transpose256(W5, W5t, 1024, 256, (b5 & 7) * 32, (b5 >> 3) * 32, t);
  } else {
    int i = (b - 3840) * 256 + threadIdx.x;
    logE[i] = (f16)logf(emb[i] * 256.0f);  // argmax-invariant *256 shift
  }
}

// ============ 256-tile stats epilogue, 8-wide partial slots ============
// cvt (by in 0..3) also zero-fills slots 4..7 when by==0 so consumers sum 8.
__device__ __forceinline__ void stats_epilogue8(char* lds, f32x4 (&acc)[8][4],
                                                f32x2* __restrict__ outPart,
                                                int bm0, int zfill) {
  const int tid = threadIdx.x;
  const int lane = tid & 63;
  const int wid = tid >> 6;
  const int wm = wid >> 2, wn = wid & 3;
  const int r0 = (lane >> 4) * 4;
  const int cc = lane & 15;
  __builtin_amdgcn_s_barrier();
  float* stp = (float*)lds;
  float* stq = (float*)(lds + 4096);
#pragma unroll
  for (int mi = 0; mi < 8; ++mi) {
#pragma unroll
    for (int j = 0; j < 4; ++j) {
      float s = 0.f, q = 0.f;
#pragma unroll
      for (int ni = 0; ni < 4; ++ni) {
        float v = acc[mi][ni][j];
        s += v; q += v * v;
      }
#pragma unroll
      for (int d = 1; d < 16; d <<= 1) { s += __shfl_xor(s, d); q += __shfl_xor(q, d); }
      if (cc == 0) {
        int rl = wm * 128 + mi * 16 + r0 + j;
        stp[rl * 4 + wn] = s;
        stq[rl * 4 + wn] = q;
      }
    }
  }
  __syncthreads();
  if (tid < 256) {
    float s = stp[tid * 4] + stp[tid * 4 + 1] + stp[tid * 4 + 2] + stp[tid * 4 + 3];
    float q = stq[tid * 4] + stq[tid * 4 + 1] + stq[tid * 4 + 2] + stq[tid * 4 + 3];
    f32x2 pr; pr[0] = s; pr[1] = q;
    outPart[(size_t)(bm0 + tid) * 8 + blockIdx.y] = pr;
    if (zfill && blockIdx.y == 0) {
      f32x2 zz; zz[0] = 0.f; zz[1] = 0.f;
#pragma unroll
      for (int k = 4; k < 8; ++k) outPart[(size_t)(bm0 + tid) * 8 + k] = zz;
    }
  }
}

// ============ shared 256x256 GEMM core (plain A), 2-barrier/K-tile ============
__device__ __forceinline__ void gemm256_core(
    const f16* __restrict__ A, const f16* __restrict__ Bt,
    char* lds, int bm0, int bn0, int K, f32x4 (&acc)[8][4]) {
  const int tid = threadIdx.x;
  const int lane = tid & 63;
  const int wid = tid >> 6;
  const int wm = wid >> 2;
  const int wn = wid & 3;
  const int NT = K >> 6;

  const int slin = tid * 16;
  const int lrow = slin >> 7;
  const int scol = (slin & 127) ^ ((lrow & 7) << 4);
  const char* Ab = (const char*)A;
  const char* Bb = (const char*)Bt;
  const uint32_t rs = (uint32_t)K * 2;

  const int klo = (lane >> 4) * 16;
  const int sw = (lane & 7) << 4;
  const uint32_t kx0 = (uint32_t)(klo ^ sw);
  const uint32_t kx1 = (uint32_t)((64 + klo) ^ sw);
  const uint32_t abase = (uint32_t)(wm * 128 + (lane & 15)) * 128;
  const uint32_t bbase = (uint32_t)(wn * 64 + (lane & 15)) * 128;

#pragma unroll
  for (int i = 0; i < 8; ++i)
#pragma unroll
    for (int j = 0; j < 4; ++j) acc[i][j] = 0.0f;

#define LDSA(buf) (lds + (buf)*32768)
#define LDSB(buf) (lds + 65536 + (buf)*32768)
#define STAGE_A(t, h)                                                              \
  {                                                                                \
    const char* src = Ab + (size_t)(bm0 + (h)*128 + lrow) * rs + ((t) << 7) + scol;\
    char* dst = LDSA((t)&1) + (h)*16384 + slin;                                    \
    gload_lds16(src, dst);                                                         \
    gload_lds16(src + (size_t)64 * rs, dst + 8192);                                \
  }
#define STAGE_B(t, h)                                                              \
  {                                                                                \
    const char* src = Bb + (size_t)(bn0 + (h)*128 + lrow) * rs + ((t) << 7) + scol;\
    char* dst = LDSB((t)&1) + (h)*16384 + slin;                                    \
    gload_lds16(src, dst);                                                         \
    gload_lds16(src + (size_t)64 * rs, dst + 8192);                                \
  }
#define HALF1(Acur, Bcur)                                                          \
  _Pragma("unroll") for (int ni = 0; ni < 4; ++ni) {                               \
    bF[ni][0] = *(const f16x8*)((Bcur) + bbase + ni * 2048 + kx0);                 \
    bF[ni][1] = *(const f16x8*)((Bcur) + bbase + ni * 2048 + kx1);                 \
  }                                                                                \
  {                                                                                \
    f16x8 aF[4][2];                                                                \
    _Pragma("unroll") for (int mi = 0; mi < 4; ++mi) {                             \
      aF[mi][0] = *(const f16x8*)((Acur) + abase + mi * 2048 + kx0);               \
      aF[mi][1] = *(const f16x8*)((Acur) + abase + mi * 2048 + kx1);               \
    }                                                                              \
    __builtin_amdgcn_s_setprio(1);                                                 \
    _Pragma("unroll") for (int mi = 0; mi < 4; ++mi)                               \
        _Pragma("unroll") for (int ni = 0; ni < 4; ++ni) {                         \
          acc[mi][ni] = mfma16(aF[mi][0], bF[ni][0], acc[mi][ni]);                 \
          acc[mi][ni] = mfma16(aF[mi][1], bF[ni][1], acc[mi][ni]);                 \
        }                                                                          \
    __builtin_amdgcn_s_setprio(0);                                                 \
  }
#define HALF2(Acur)                                                                \
  {                                                                                \
    f16x8 aF[4][2];                                                                \
    _Pragma("unroll") for (int mi = 0; mi < 4; ++mi) {                             \
      aF[mi][0] = *(const f16x8*)((Acur) + abase + (mi + 4) * 2048 + kx0);         \
      aF[mi][1] = *(const f16x8*)((Acur) + abase + (mi + 4) * 2048 + kx1);         \
    }                                                                              \
    __builtin_amdgcn_s_setprio(1);                                                 \
    _Pragma("unroll") for (int mi = 0; mi < 4; ++mi)                               \
        _Pragma("unroll") for (int ni = 0; ni < 4; ++ni) {                         \
          acc[mi + 4][ni] = mfma16(aF[mi][0], bF[ni][0], acc[mi + 4][ni]);         \
          acc[mi + 4][ni] = mfma16(aF[mi][1], bF[ni][1], acc[mi + 4][ni]);         \
        }                                                                          \
    __builtin_amdgcn_s_setprio(0);                                                 \
  }

  STAGE_A(0, 0); STAGE_A(0, 1); STAGE_B(0, 0); STAGE_B(0, 1);
  STAGE_B(1, 0); STAGE_B(1, 1);
  asm volatile("s_waitcnt vmcnt(4)");
  __builtin_amdgcn_s_barrier();
  __builtin_amdgcn_sched_barrier(0);

  f16x8 bF[4][2];
  for (int t = 0; t < NT - 2; ++t) {
    const char* Acur = LDSA(t & 1);
    const char* Bcur = LDSB(t & 1);
    STAGE_A(t + 1, 0); STAGE_A(t + 1, 1);
    HALF1(Acur, Bcur)
    __builtin_amdgcn_s_barrier();
    __builtin_amdgcn_sched_barrier(0);
    STAGE_B(t + 2, 0); STAGE_B(t + 2, 1);
    HALF2(Acur)
    asm volatile("s_waitcnt vmcnt(4)");
    __builtin_amdgcn_s_barrier();
    __builtin_amdgcn_sched_barrier(0);
  }
  {
    const char* Acur = LDSA((NT - 2) & 1);
    const char* Bcur = LDSB((NT - 2) & 1);
    STAGE_A(NT - 1, 0); STAGE_A(NT - 1, 1);
    HALF1(Acur, Bcur)
    __builtin_amdgcn_s_barrier();
    __builtin_amdgcn_sched_barrier(0);
    HALF2(Acur)
    asm volatile("s_waitcnt vmcnt(0)");
    __builtin_amdgcn_s_barrier();
    __builtin_amdgcn_sched_barrier(0);
  }
  {
    const char* Acur = LDSA((NT - 1) & 1);
    const char* Bcur = LDSB((NT - 1) & 1);
    HALF1(Acur, Bcur)
    HALF2(Acur)
  }
#undef STAGE_A
#undef HALF1
#undef HALF2
#undef LDSA
#undef LDSB
#undef STAGE_B
}

// ---- div-GEMM: per-row argmax partials over 64-col chunks ----
__global__ __launch_bounds__(512, 2) void k_gemm256_div(
    const f16* __restrict__ A, const f16* __restrict__ Bt,
    float* __restrict__ part_val, int* __restrict__ part_idx, int N, int K) {
  __shared__ char lds[131072];
  const int bm0 = blockIdx.x * 256;
  const int bn0 = blockIdx.y * 256;
  f32x4 acc[8][4];
  gemm256_core(A, Bt, lds, bm0, bn0, K, acc);

  const int lane = threadIdx.x & 63;
  const int wid = threadIdx.x >> 6;
  const int wm = wid >> 2, wn = wid & 3;
  const int r0 = (lane >> 4) * 4;
  const int cc = lane & 15;
  const int nch = N >> 6;
  const int chunk = (bn0 >> 6) + wn;
#pragma unroll
  for (int mi = 0; mi < 8; ++mi) {
#pragma unroll
    for (int j = 0; j < 4; ++j) {
      float v = acc[mi][0][j];
      int c = cc;
#pragma unroll
      for (int ni = 1; ni < 4; ++ni) {
        float v2 = acc[mi][ni][j];
        int c2 = ni * 16 + cc;
        if (v2 > v) { v = v2; c = c2; }
      }
#pragma unroll
      for (int d = 1; d < 16; d <<= 1) {
        float ov = __shfl_xor(v, d);
        int oc = __shfl_xor(c, d);
        if (ov > v || (ov == v && oc < c)) { v = ov; c = oc; }
      }
      if (cc == 0) {
        int r = bm0 + wm * 128 + mi * 16 + r0 + j;
        part_val[r * nch + chunk] = v;
        part_idx[r * nch + chunk] = bn0 + wn * 64 + c;
      }
    }
  }
}

// ---- L1: A = x (f32), fused cvt in A-stage; 8-wide stats; h store ----
__global__ __launch_bounds__(512, 2) void k_gemm256_cvt(
    const float* __restrict__ A, const f16* __restrict__ Bt,
    f16* __restrict__ O, f32x2* __restrict__ outPart, int N, int K) {
  __shared__ char lds[131072];
  const int tid = threadIdx.x;
  const int lane = tid & 63;
  const int wid = tid >> 6;
  const int wm = wid >> 2;
  const int wn = wid & 3;
  const int bm0 = blockIdx.x * 256;
  const int bn0 = blockIdx.y * 256;
  const int NT = K >> 6;

  const int slin = tid * 16;
  const int lrow = slin >> 7;
  const int scol = (slin & 127) ^ ((lrow & 7) << 4);
  const char* Ab = (const char*)A;        // f32, row stride K*4
  const char* Bb = (const char*)Bt;
  const uint32_t rsA = (uint32_t)K * 4;
  const uint32_t rs = (uint32_t)K * 2;

  const int klo = (lane >> 4) * 16;
  const int sw = (lane & 7) << 4;
  const uint32_t kx0 = (uint32_t)(klo ^ sw);
  const uint32_t kx1 = (uint32_t)((64 + klo) ^ sw);
  const uint32_t abase = (uint32_t)(wm * 128 + (lane & 15)) * 128;
  const uint32_t bbase = (uint32_t)(wn * 64 + (lane & 15)) * 128;

  const int alrow = tid >> 3;
  const uint32_t acolbF = (uint32_t)(tid & 7) * 32;
  const uint32_t awcol = ((uint32_t)(tid & 7) * 16) ^ (uint32_t)((alrow & 7) << 4);
  f32x4 arf[4][2];

  f32x4 acc[8][4];
#pragma unroll
  for (int i = 0; i < 8; ++i)
#pragma unroll
    for (int j = 0; j < 4; ++j) acc[i][j] = 0.0f;

#define LDSA(buf) (lds + (buf)*32768)
#define LDSB(buf) (lds + 65536 + (buf)*32768)
#define STAGE_B(t, h)                                                              \
  {                                                                                \
    const char* src = Bb + (size_t)(bn0 + (h)*128 + lrow) * rs + ((t) << 7) + scol;\
    char* dst = LDSB((t)&1) + (h)*16384 + slin;                                    \
    gload_lds16(src, dst);                                                         \
    gload_lds16(src + (size_t)64 * rs, dst + 8192);                                \
  }
#define A_ISSUE(t1)                                                               \
  {                                                                               \
    const char* base_ = Ab + (size_t)(bm0 + alrow) * rsA + ((size_t)(t1) << 8) + acolbF; \
    _Pragma("unroll") for (int i = 0; i < 4; ++i) {                               \
      arf[i][0] = *(const f32x4*)(base_ + (size_t)(i * 64) * rsA);                \
      arf[i][1] = *(const f32x4*)(base_ + (size_t)(i * 64) * rsA + 16);           \
    }                                                                             \
  }
#define A_WRITE(t1)                                                               \
  {                                                                               \
    char* wb_ = LDSA((t1)&1);                                                     \
    _Pragma("unroll") for (int i = 0; i < 4; ++i) {                               \
      f16x8 o;                                                                    \
      _Pragma("unroll") for (int e = 0; e < 4; ++e) {                             \
        o[e] = (f16)arf[i][0][e];                                                 \
        o[e + 4] = (f16)arf[i][1][e];                                             \
      }                                                                           \
      *(f16x8*)(wb_ + (i >> 1) * 16384 + (alrow + (i & 1) * 64) * 128 + awcol) = o; \
    }                                                                             \
  }
#define HALF1(Acur, Bcur)                                                          \
  _Pragma("unroll") for (int ni = 0; ni < 4; ++ni) {                               \
    bF[ni][0] = *(const f16x8*)((Bcur) + bbase + ni * 2048 + kx0);                 \
    bF[ni][1] = *(const f16x8*)((Bcur) + bbase + ni * 2048 + kx1);                 \
  }                                                                                \
  {                                                                                \
    f16x8 aF[4][2];                                                                \
    _Pragma("unroll") for (int mi = 0; mi < 4; ++mi) {                             \
      aF[mi][0] = *(const f16x8*)((Acur) + abase + mi * 2048 + kx0);               \
      aF[mi][1] = *(const f16x8*)((Acur) + abase + mi * 2048 + kx1);               \
    }                                                                              \
    __builtin_amdgcn_s_setprio(1);                                                 \
    _Pragma("unroll") for (int mi = 0; mi < 4; ++mi)                               \
        _Pragma("unroll") for (int ni = 0; ni < 4; ++ni) {                         \
          acc[mi][ni] = mfma16(aF[mi][0], bF[ni][0], acc[mi][ni]);                 \
          acc[mi][ni] = mfma16(aF[mi][1], bF[ni][1], acc[mi][ni]);                 \
        }                                                                          \
    __builtin_amdgcn_s_setprio(0);                                                 \
  }
#define HALF2(Acur)                                                                \
  {                                                                                \
    f16x8 aF[4][2];                                                                \
    _Pragma("unroll") for (int mi = 0; mi < 4; ++mi) {                             \
      aF[mi][0] = *(const f16x8*)((Acur) + abase + (mi + 4) * 2048 + kx0);         \
      aF[mi][1] = *(const f16x8*)((Acur) + abase + (mi + 4) * 2048 + kx1);         \
    }                                                                              \
    __builtin_amdgcn_s_setprio(1);                                                 \
    _Pragma("unroll") for (int mi = 0; mi < 4; ++mi)                               \
        _Pragma("unroll") for (int ni = 0; ni < 4; ++ni) {                         \
          acc[mi + 4][ni] = mfma16(aF[mi][0], bF[ni][0], acc[mi + 4][ni]);         \
          acc[mi + 4][ni] = mfma16(aF[mi][1], bF[ni][1], acc[mi + 4][ni]);         \
        }                                                                          \
    __builtin_amdgcn_s_setprio(0);                                                 \
  }

  A_ISSUE(0)
  STAGE_B(0, 0); STAGE_B(0, 1); STAGE_B(1, 0); STAGE_B(1, 1);
  asm volatile("s_waitcnt vmcnt(8)");
  A_WRITE(0)
  asm volatile("s_waitcnt vmcnt(4) lgkmcnt(0)");
  __builtin_amdgcn_s_barrier();
  __builtin_amdgcn_sched_barrier(0);

  f16x8 bF[4][2];
  for (int t = 0; t < NT - 2; ++t) {
    const char* Acur = LDSA(t & 1);
    const char* Bcur = LDSB(t & 1);
    A_ISSUE(t + 1)
    HALF1(Acur, Bcur)
    __builtin_amdgcn_s_barrier();
    __builtin_amdgcn_sched_barrier(0);
    STAGE_B(t + 2, 0); STAGE_B(t + 2, 1);
    HALF2(Acur)
    asm volatile("s_waitcnt vmcnt(4)");
    A_WRITE(t + 1)
    asm volatile("s_waitcnt lgkmcnt(0)");
    __builtin_amdgcn_s_barrier();
    __builtin_amdgcn_sched_barrier(0);
  }
  {
    const char* Acur = LDSA((NT - 2) & 1);
    const char* Bcur = LDSB((NT - 2) & 1);
    A_ISSUE(NT - 1)
    HALF1(Acur, Bcur)
    __builtin_amdgcn_s_barrier();
    __builtin_amdgcn_sched_barrier(0);
    HALF2(Acur)
    asm volatile("s_waitcnt vmcnt(0)");
    A_WRITE(NT - 1)
    asm volatile("s_waitcnt lgkmcnt(0)");
    __builtin_amdgcn_s_barrier();
    __builtin_amdgcn_sched_barrier(0);
  }
  {
    const char* Acur = LDSA((NT - 1) & 1);
    const char* Bcur = LDSB((NT - 1) & 1);
    HALF1(Acur, Bcur)
    HALF2(Acur)
  }
#undef STAGE_B
#undef A_ISSUE
#undef A_WRITE
#undef HALF1
#undef HALF2
#undef LDSA
#undef LDSB

  stats_epilogue8(lds, acc, outPart, bm0, 1);

  const int r0 = (lane >> 4) * 4;
  const int cc = lane & 15;
#pragma unroll
  for (int mi = 0; mi < 8; ++mi) {
#pragma unroll
    for (int ni = 0; ni < 4; ++ni) {
      int r = bm0 + wm * 128 + mi * 16 + r0;
      int c = bn0 + wn * 64 + ni * 16 + cc;
#pragma unroll
      for (int j = 0; j < 4; ++j)
        O[(size_t)(r + j) * N + c] = (f16)acc[mi][ni][j];
    }
  }
}

// ======== consumer-LN fused 128x128 GEMM + 8-wide stats (L2/L3/L4) ========
// BM=BN=128, BK=64, 256 threads (4 waves 2Mx2N), LDS 68KB -> 2 blocks/CU.
// Same 2-barrier pipelined schedule + serial-tail packed-f16 A_WRITE as the
// 256-tile ln (R17 measured-best); inter-block overlap fills barrier stalls.
__global__ __launch_bounds__(256, 2) void k_gemm128_ln(
    const f16* __restrict__ A, const f16* __restrict__ Bt,
    f16* __restrict__ O, const float* __restrict__ gw,
    const float* __restrict__ bw, const f32x2* __restrict__ inPart,
    f32x2* __restrict__ outPart, int N, int K) {
  __shared__ char lds[69632];  // A dbuf 2x16K @0, B dbuf 2x16K @32768, g/b 4K @65536
  const int GB = 65536;
  const int tid = threadIdx.x;
  const int lane = tid & 63;
  const int wid = tid >> 6;
  const int wm = wid >> 1;   // 0..1
  const int wn = wid & 1;    // 0..1
  const int bm0 = blockIdx.x * 128;
  const int bn0 = blockIdx.y * 128;
  const int NT = K >> 6;

  // staging addressing (B): 16KB/tile, 4 passes of 256x16B
  const char* Ab = (const char*)A;
  const char* Bb = (const char*)Bt;
  const uint32_t rs = (uint32_t)K * 2;

  const int klo = (lane >> 4) * 16;
  const int sw = (lane & 7) << 4;
  const uint32_t kx0 = (uint32_t)(klo ^ sw);
  const uint32_t kx1 = (uint32_t)((64 + klo) ^ sw);
  const uint32_t abase = (uint32_t)(wm * 64 + (lane & 15)) * 128;
  const uint32_t bbase = (uint32_t)(wn * 64 + (lane & 15)) * 128;

  const int alrow = tid >> 3;  // 0..31
  const uint32_t acolb = (uint32_t)(tid & 7) * 16;
  const uint32_t awcol = acolb ^ (uint32_t)((alrow & 7) << 4);
  f16 aSh[4], cSh[4];
  f16x8 ar[4];

  f32x4 acc[4][4];
#pragma unroll
  for (int i = 0; i < 4; ++i)
#pragma unroll
    for (int j = 0; j < 4; ++j) acc[i][j] = 0.0f;

#define LDSA(buf) (lds + (buf)*16384)
#define LDSB(buf) (lds + 32768 + (buf)*16384)
#define STAGE_B(t)                                                                \
  {                                                                               \
    char* bdst = LDSB((t)&1);                                                     \
    _Pragma("unroll") for (int i = 0; i < 4; ++i) {                               \
      int lin = i * 4096 + tid * 16;                                              \
      int row = lin >> 7;                                                         \
      int col = (lin & 127) ^ ((row & 7) << 4);                                   \
      gload_lds16(Bb + (size_t)(bn0 + row) * rs + ((size_t)(t) << 7) + col,       \
                  bdst + lin);                                                    \
    }                                                                             \
  }
#define A_ISSUE(t1)                                                               \
  {                                                                               \
    const char* base_ = Ab + (size_t)(bm0 + alrow) * rs + ((size_t)(t1) << 7) + acolb; \
    ar[0] = *(const f16x8*)(base_);                                               \
    ar[1] = *(const f16x8*)(base_ + (size_t)32 * rs);                             \
    ar[2] = *(const f16x8*)(base_ + (size_t)64 * rs);                             \
    ar[3] = *(const f16x8*)(base_ + (size_t)96 * rs);                             \
  }
#define A_WRITE(t1)                                                               \
  {                                                                               \
    uint32_t off_ = GB + (uint32_t)(t1)*128 + (uint32_t)(tid & 7) * 16;           \
    f16x8 gr = *(const f16x8*)(lds + off_);                                       \
    f16x8 br = *(const f16x8*)(lds + off_ + 2048);                                \
    char* wb_ = LDSA((t1)&1);                                                     \
    _Pragma("unroll") for (int i = 0; i < 4; ++i) {                               \
      f16x8 aS8, cS8, zz;                                                         \
      _Pragma("unroll") for (int p = 0; p < 8; ++p) {                             \
        aS8[p] = aSh[i]; cS8[p] = cSh[i]; zz[p] = (f16)0.f;                       \
      }                                                                           \
      f16x8 tt = ar[i] * aS8 + cS8;                                               \
      tt = tt * gr + br;                                                          \
      tt = __builtin_elementwise_max(tt, zz);                                     \
      *(f16x8*)(wb_ + (alrow + i * 32) * 128 + awcol) = tt;                       \
    }                                                                             \
  }
// HALF1: B frags (8 reads) + A frags mi=0,1; 16 MFMA. HALF2: mi=2,3; 16 MFMA.
#define HALF1(Acur, Bcur)                                                          \
  _Pragma("unroll") for (int ni = 0; ni < 4; ++ni) {                               \
    bF[ni][0] = *(const f16x8*)((Bcur) + bbase + ni * 2048 + kx0);                 \
    bF[ni][1] = *(const f16x8*)((Bcur) + bbase + ni * 2048 + kx1);                 \
  }                                                                                \
  {                                                                                \
    f16x8 aF[2][2];                                                                \
    _Pragma("unroll") for (int mi = 0; mi < 2; ++mi) {                             \
      aF[mi][0] = *(const f16x8*)((Acur) + abase + mi * 2048 + kx0);               \
      aF[mi][1] = *(const f16x8*)((Acur) + abase + mi * 2048 + kx1);               \
    }                                                                              \
    __builtin_amdgcn_s_setprio(1);                                                 \
    _Pragma("unroll") for (int mi = 0; mi < 2; ++mi)                               \
        _Pragma("unroll") for (int ni = 0; ni < 4; ++ni) {                         \
          acc[mi][ni] = mfma16(aF[mi][0], bF[ni][0], acc[mi][ni]);                 \
          acc[mi][ni] = mfma16(aF[mi][1], bF[ni][1], acc[mi][ni]);                 \
        }                                                                          \
    __builtin_amdgcn_s_setprio(0);                                                 \
  }
#define HALF2(Acur)                                                                \
  {                                                                                \
    f16x8 aF[2][2];                                                                \
    _Pragma("unroll") for (int mi = 0; mi < 2; ++mi) {                             \
      aF[mi][0] = *(const f16x8*)((Acur) + abase + (mi + 2) * 2048 + kx0);         \
      aF[mi][1] = *(const f16x8*)((Acur) + abase + (mi + 2) * 2048 + kx1);         \
    }                                                                              \
    __builtin_amdgcn_s_setprio(1);                                                 \
    _Pragma("unroll") for (int mi = 0; mi < 2; ++mi)                               \
        _Pragma("unroll") for (int ni = 0; ni < 4; ++ni) {                         \
          acc[mi + 2][ni] = mfma16(aF[mi][0], bF[ni][0], acc[mi + 2][ni]);         \
          acc[mi + 2][ni] = mfma16(aF[mi][1], bF[ni][1], acc[mi + 2][ni]);         \
        }                                                                          \
    __builtin_amdgcn_s_setprio(0);                                                 \
  }

  // prologue: g/b -> LDS as f16; stats; A(0) regs + B(0),B(1)
  {
    f32x4 g4 = ((const f32x4*)gw)[tid];
    f32x4 b4 = ((const f32x4*)bw)[tid];
    f16x4 gh, bh;
#pragma unroll
    for (int e = 0; e < 4; ++e) { gh[e] = (f16)g4[e]; bh[e] = (f16)b4[e]; }
    ((f16x4*)(lds + GB))[tid] = gh;
    ((f16x4*)(lds + GB + 2048))[tid] = bh;
  }
#pragma unroll
  for (int i = 0; i < 4; ++i) {
    float rstd, shift;
    ln_coeff(inPart, bm0 + alrow + i * 32, &rstd, &shift);
    aSh[i] = (f16)rstd;
    cSh[i] = (f16)shift;
  }
  __builtin_amdgcn_sched_barrier(0);
  A_ISSUE(0)
  STAGE_B(0) STAGE_B(1)
  __builtin_amdgcn_sched_barrier(0);
  asm volatile("s_waitcnt lgkmcnt(0)");
  __builtin_amdgcn_s_barrier();               // g/b visible to all waves
  asm volatile("s_waitcnt vmcnt(8)");          // ar(0) landed
  A_WRITE(0)
  asm volatile("s_waitcnt vmcnt(4) lgkmcnt(0)");  // B(0) landed, A(0) written
  __builtin_amdgcn_s_barrier();
  __builtin_amdgcn_sched_barrier(0);

  f16x8 bF[4][2];
  for (int t = 0; t < NT; ++t) {
    const char* Acur = LDSA(t & 1);
    const char* Bcur = LDSB(t & 1);

    if (t + 1 < NT) { A_ISSUE(t + 1) }
    HALF1(Acur, Bcur)
    __builtin_amdgcn_s_barrier();
    __builtin_amdgcn_sched_barrier(0);

    if (t + 2 < NT) { STAGE_B(t + 2) }
    HALF2(Acur)
    if (t + 1 < NT) {
      if (t + 2 < NT) { asm volatile("s_waitcnt vmcnt(4)"); }
      else            { asm volatile("s_waitcnt vmcnt(0)"); }
      A_WRITE(t + 1)
      asm volatile("s_waitcnt lgkmcnt(0)");
      __builtin_amdgcn_s_barrier();
      __builtin_amdgcn_sched_barrier(0);
    }
  }
#undef STAGE_B
#undef A_ISSUE
#undef A_WRITE
#undef HALF1
#undef HALF2
#undef LDSA
#undef LDSB

  // ---- 8-wide stats epilogue (128 rows, 2 wn partials) ----
  const int r0 = (lane >> 4) * 4;
  const int cc = lane & 15;
  __builtin_amdgcn_s_barrier();
  {
    float* stp = (float*)lds;            // [128][2]
    float* stq = (float*)(lds + 1024);   // [128][2]
#pragma unroll
    for (int mi = 0; mi < 4; ++mi) {
#pragma unroll
      for (int j = 0; j < 4; ++j) {
        float s = 0.f, q = 0.f;
#pragma unroll
        for (int ni = 0; ni < 4; ++ni) {
          float v = acc[mi][ni][j];
          s += v; q += v * v;
        }
#pragma unroll
        for (int d = 1; d < 16; d <<= 1) { s += __shfl_xor(s, d); q += __shfl_xor(q, d); }
        if (cc == 0) {
          int rl = wm * 64 + mi * 16 + r0 + j;
          stp[rl * 2 + wn] = s;
          stq[rl * 2 + wn] = q;
        }
      }
    }
    __syncthreads();
    if (tid < 128) {
      float s = stp[tid * 2] + stp[tid * 2 + 1];
      float q = stq[tid * 2] + stq[tid * 2 + 1];
      f32x2 pr; pr[0] = s; pr[1] = q;
      outPart[(size_t)(bm0 + tid) * 8 + blockIdx.y] = pr;
    }
  }

  // ---- h store ----
#pragma unroll
  for (int mi = 0; mi < 4; ++mi) {
#pragma unroll
    for (int ni = 0; ni < 4; ++ni) {
      int r = bm0 + wm * 64 + mi * 16 + r0;
      int c = bn0 + wn * 64 + ni * 16 + cc;
#pragma unroll
      for (int j = 0; j < 4; ++j)
        O[(size_t)(r + j) * N + c] = (f16)acc[mi][ni][j];
    }
  }
}

// ======== fused LN(h4) -> G5 -> softmax, pipelined B dbuf, packed-f16 ========
__global__ __launch_bounds__(256) void k_gemm_sm(
    const f16* __restrict__ A, const f16* __restrict__ Bt,
    const float* __restrict__ gw, const float* __restrict__ bw,
    const f32x2* __restrict__ inPart, const float* __restrict__ bias,
    float* __restrict__ z, f16* __restrict__ ep, float* __restrict__ sm) {
  const int K = 1024;
  __shared__ char lds[77824];  // A 8K @0, B dbuf 2x32K @8192, g/b 4K @73728
  const int GBS = 73728;
  char* ldsA = lds;
  const int tid = threadIdx.x;
  const int lane = tid & 63;
  const int wn = tid >> 6;
  const int bm0 = blockIdx.x * 64;
  const char* Ab = (const char*)A;
  const char* Bb = (const char*)Bt;
  const uint32_t rs = (uint32_t)K * 2;
  const int cc = lane & 15;

  {
    f32x4 g4 = ((const f32x4*)gw)[tid];
    f32x4 b4 = ((const f32x4*)bw)[tid];
    f16x4 gh, bh;
#pragma unroll
    for (int e = 0; e < 4; ++e) { gh[e] = (f16)g4[e]; bh[e] = (f16)b4[e]; }
    ((f16x4*)(lds + GBS))[tid] = gh;
    ((f16x4*)(lds + GBS + 2048))[tid] = bh;
  }

  const int ar0 = tid >> 3;
  f16 aSh[2], cSh[2];
#pragma unroll
  for (int i = 0; i < 2; ++i) {
    float rstd, shift;
    ln_coeff(inPart, bm0 + ar0 + i * 32, &rstd, &shift);
    aSh[i] = (f16)rstd;
    cSh[i] = (f16)shift;
  }
  const uint32_t acolb = (uint32_t)(tid & 7) * 16;
  const uint32_t awcol = acolb ^ (uint32_t)((ar0 & 7) << 4);

  uint32_t ra[2][4], rb[2][4];
  {
    const int sww = (lane & 7) << 4;
    const int gk = lane & 48;
#pragma unroll
    for (int kk = 0; kk < 2; ++kk) {
#pragma unroll
      for (int i = 0; i < 4; ++i) {
        uint32_t kb = (uint32_t)((kk * 64 + gk) ^ sww);
        ra[kk][i] = (uint32_t)(i * 16 + cc) * 128 + kb;
        rb[kk][i] = (uint32_t)(wn * 64 + i * 16 + cc) * 128 + kb;
      }
    }
  }

  f32x4 acc[4][4];
#pragma unroll
  for (int i = 0; i < 4; ++i)
#pragma unroll
    for (int j = 0; j < 4; ++j) acc[i][j] = 0.0f;

#define STAGE_BS(t)                                                               \
  {                                                                               \
    char* bdst = lds + 8192 + ((t)&1) * 32768;                                    \
    _Pragma("unroll") for (int i = 0; i < 8; ++i) {                               \
      int lin = i * 4096 + tid * 16;                                              \
      int row = lin >> 7;                                                         \
      int col = (lin & 127) ^ ((row & 7) << 4);                                   \
      gload_lds16(Bb + (size_t)row * rs + ((size_t)(t) << 7) + col, bdst + lin);  \
    }                                                                             \
  }

  STAGE_BS(0)
  asm volatile("s_waitcnt lgkmcnt(0)");
  __builtin_amdgcn_s_barrier();   // g/b visible
  __builtin_amdgcn_sched_barrier(0);

  for (int t = 0; t < 16; ++t) {
    const char* abase_ = Ab + (size_t)(bm0 + ar0) * rs + ((size_t)t << 7) + acolb;
    f16x8 a0 = *(const f16x8*)abase_;
    f16x8 a1 = *(const f16x8*)(abase_ + (size_t)32 * rs);
    if (t + 1 < 16) { STAGE_BS(t + 1) }
    if (t + 1 < 16) { asm volatile("s_waitcnt vmcnt(8)"); }  // drains B(t)+a0,a1
    else            { asm volatile("s_waitcnt vmcnt(0)"); }
    {
      uint32_t off_ = GBS + (uint32_t)t * 128 + (uint32_t)(tid & 7) * 16;
      f16x8 gr = *(const f16x8*)(lds + off_);
      f16x8 br = *(const f16x8*)(lds + off_ + 2048);
      f16x8 aS0, cS0, aS1, cS1, zz;
#pragma unroll
      for (int p = 0; p < 8; ++p) {
        aS0[p] = aSh[0]; cS0[p] = cSh[0];
        aS1[p] = aSh[1]; cS1[p] = cSh[1];
        zz[p] = (f16)0.f;
      }
      f16x8 t0 = a0 * aS0 + cS0;
      f16x8 t1 = a1 * aS1 + cS1;
      t0 = t0 * gr + br;
      t1 = t1 * gr + br;
      t0 = __builtin_elementwise_max(t0, zz);
      t1 = __builtin_elementwise_max(t1, zz);
      *(f16x8*)(ldsA + ar0 * 128 + awcol) = t0;
      *(f16x8*)(ldsA + (ar0 + 32) * 128 + awcol) = t1;
    }
    asm volatile("s_waitcnt lgkmcnt(0)");
    __builtin_amdgcn_s_barrier();   // ldsA written by all; B(t) landed
    __builtin_amdgcn_sched_barrier(0);
    {
      const char* Bcur = lds + 8192 + (t & 1) * 32768;
#pragma unroll
      for (int kk = 0; kk < 2; ++kk) {
        f16x8 af[4], bfv[4];
#pragma unroll
        for (int i = 0; i < 4; ++i) af[i] = *(const f16x8*)(ldsA + ra[kk][i]);
#pragma unroll
        for (int i = 0; i < 4; ++i) bfv[i] = *(const f16x8*)(Bcur + rb[kk][i]);
#pragma unroll
        for (int mi = 0; mi < 4; ++mi)
#pragma unroll
          for (int ni = 0; ni < 4; ++ni)
            acc[mi][ni] = mfma16(af[mi], bfv[ni], acc[mi][ni]);
      }
    }
    __builtin_amdgcn_s_barrier();   // all reads of ldsA / B(t) done before overwrite
    __builtin_amdgcn_sched_barrier(0);
  }
#undef STAGE_BS

  // ---- softmax epilogue over full 256-wide rows ----
  __syncthreads();
  float* stm = (float*)lds;
  float* sts = (float*)(lds + 1024);
  float* rowm = (float*)(lds + 2048);
  float* rows_ = (float*)(lds + 2304);

  const int r0 = (lane >> 4) * 4;
  float bvv[4];
#pragma unroll
  for (int ni = 0; ni < 4; ++ni) bvv[ni] = bias[wn * 64 + ni * 16 + cc];

#pragma unroll
  for (int mi = 0; mi < 4; ++mi) {
#pragma unroll
    for (int j = 0; j < 4; ++j) {
      float m = -3.4e38f;
#pragma unroll
      for (int ni = 0; ni < 4; ++ni) m = fmaxf(m, acc[mi][ni][j] + bvv[ni]);
#pragma unroll
      for (int d = 1; d < 16; d <<= 1) m = fmaxf(m, __shfl_xor(m, d));
      if (cc == 0) stm[wn * 64 + mi * 16 + r0 + j] = m;
    }
  }
  __syncthreads();
  if (tid < 64) {
    float m = fmaxf(fmaxf(stm[tid], stm[64 + tid]), fmaxf(stm[128 + tid], stm[192 + tid]));
    rowm[tid] = m;
  }
  __syncthreads();
#pragma unroll
  for (int mi = 0; mi < 4; ++mi) {
#pragma unroll
    for (int j = 0; j < 4; ++j) {
      int r = mi * 16 + r0 + j;
      float m = rowm[r];
      float s = 0.f;
#pragma unroll
      for (int ni = 0; ni < 4; ++ni) s += expf(acc[mi][ni][j] + bvv[ni] - m);
#pragma unroll
      for (int d = 1; d < 16; d <<= 1) s += __shfl_xor(s, d);
      if (cc == 0) sts[wn * 64 + r] = s;
    }
  }
  __syncthreads();
  if (tid < 64) {
    float s = sts[tid] + sts[64 + tid] + sts[128 + tid] + sts[192 + tid];
    rows_[tid] = s;
    sm[bm0 + tid] = rowm[tid] + logf(s);
  }
  __syncthreads();
#pragma unroll
  for (int mi = 0; mi < 4; ++mi) {
#pragma unroll
    for (int j = 0; j < 4; ++j) {
      int r = mi * 16 + r0 + j;
      float m = rowm[r];
      float inv = 1.0f / rows_[r];
      float* zp = z + (size_t)(bm0 + r) * 256;
      f16* epp = ep + (size_t)(bm0 + r) * 256;
#pragma unroll
      for (int ni = 0; ni < 4; ++ni) {
        int c = wn * 64 + ni * 16 + cc;
        float zz = acc[mi][ni][j] + bvv[ni];
        zp[c] = zz;
        epp[c] = (f16)(expf(zz - m) * inv);
      }
    }
  }
}

// ---------------- finalize: argmax reduce, gather q, fp32 kl from z,sm ----------------
__global__ __launch_bounds__(256) void k_final(
    const float* __restrict__ part_val, const int* __restrict__ part_idx,
    const float* __restrict__ z, const float* __restrict__ sm,
    const float* __restrict__ emb, const float* __restrict__ masks,
    float* __restrict__ q, float* __restrict__ blockloss) {
  __shared__ float ls[4];
  int lane = threadIdx.x & 63;
  int w = threadIdx.x >> 6;
  int row = blockIdx.x * 4 + w;
  float v = -3.4e38f;
  int c = 0x7fffffff;
  if (lane < 16) { v = part_val[row * 16 + lane]; c = part_idx[row * 16 + lane]; }
#pragma unroll
  for (int d = 1; d < 16; d <<= 1) {
    float ov = __shfl_xor(v, d);
    int oc = __shfl_xor(c, d);
    if (ov > v || (ov == v && oc < c)) { v = ov; c = oc; }
  }
  int code = __shfl(c, 0);
  f32x4 ev = ((const f32x4*)(emb + (size_t)code * 256))[lane];
  ((f32x4*)(q + (size_t)row * 256))[lane] = ev;
  f32x4 zv = ((const f32x4*)(z + (size_t)row * 256))[lane];
  float smr = sm[row];
  float kl = 0.f;
#pragma unroll
  for (int j = 0; j < 4; ++j) {
    float pj = zv[j] - smr;
    kl += expf(pj) * (pj - logf(ev[j]));
  }
#pragma unroll
  for (int d = 1; d < 64; d <<= 1) kl += __shfl_xor(kl, d);
  if (lane == 0) ls[w] = kl * masks[row];
  __syncthreads();
  if (threadIdx.x == 0) blockloss[blockIdx.x] = ls[0] + ls[1] + ls[2] + ls[3];
}

__global__ __launch_bounds__(256) void k_loss_reduce(const float* __restrict__ bl,
                                                     float* __restrict__ out) {
  __shared__ float s[256];
  float a = 0.f;
#pragma unroll
  for (int i = 0; i < 16; ++i) a += bl[threadIdx.x + i * 256];
  s[threadIdx.x] = a;
  __syncthreads();
  for (int st = 128; st > 0; st >>= 1) {
    if (threadIdx.x < st) s[threadIdx.x] += s[threadIdx.x + st];
    __syncthreads();
  }
  if (threadIdx.x == 0) out[0] = s[0] * (0.25f / 16.0f);
}

// ---------------- launch ----------------
extern "C" void kernel_launch(void* const* d_in, const int* in_sizes, int n_in,
                              void* d_out, int out_size, void* d_ws, size_t ws_size,
                              hipStream_t stream) {
  const float* x = (const float*)d_in[0];
  const float* masks = (const float*)d_in[1];
  const float* W1 = (const float*)d_in[2];
  const float* g1 = (const float*)d_in[3];
  const float* b1 = (const float*)d_in[4];
  const float* W2 = (const float*)d_in[5];
  const float* g2 = (const float*)d_in[6];
  const float* b2 = (const float*)d_in[7];
  const float* W3 = (const float*)d_in[8];
  const float* g3 = (const float*)d_in[9];
  const float* b3 = (const float*)d_in[10];
  const float* W4 = (const float*)d_in[11];
  const float* g4 = (const float*)d_in[12];
  const float* b4 = (const float*)d_in[13];
  const float* W5 = (const float*)d_in[14];
  const float* b5 = (const float*)d_in[15];
  const float* emb = (const float*)d_in[16];

  const int M = 16384;  // B*T
  char* ws = (char*)d_ws;
  f16* bufA = (f16*)(ws);                       // 32 MB ping
  f16* bufB = (f16*)(ws + (32ull << 20));       // 32 MB pong
  f16* W1t = (f16*)(ws + (64ull << 20));        // 1 MB  [1024][512]
  f16* W2t = (f16*)(ws + (65ull << 20));        // 2 MB
  f16* W3t = (f16*)(ws + (67ull << 20));        // 2 MB
  f16* W4t = (f16*)(ws + (69ull << 20));        // 2 MB
  f16* W5t = (f16*)(ws + (71ull << 20));        // 0.5 MB [256][1024]
  f16* logE = (f16*)(ws + (72ull << 20));       // 0.5 MB [1024][256]
  float* part_val = (float*)(ws + (73ull << 20));     // 1 MB
  int* part_idx = (int*)(ws + (74ull << 20));         // 1 MB
  float* blockloss = (float*)(ws + (75ull << 20));    // 16 KB
  float* sm = (float*)(ws + (76ull << 20));           // 64 KB
  f32x2* partA = (f32x2*)(ws + (77ull << 20));        // 1 MB [16384][8]
  f32x2* partB = (f32x2*)(ws + (78ull << 20));        // 1 MB
  f16* ep = (f16*)(ws + (16ull << 20));               // 8 MB, aliases bufA upper half

  float* z = (float*)d_out;                 // [16384][256]
  float* q = z + (size_t)M * 256;           // [16384][256]
  float* lossp = z + 2ull * M * 256;        // [1]

  k_prep<<<4864, 256, 0, stream>>>(W1, W1t, W2, W2t, W3, W3t, W4, W4t,
                                   W5, W5t, emb, logE);
  k_gemm256_cvt<<<dim3(64, 4), 512, 0, stream>>>(x, W1t, bufA, partA, 1024, 512);
  k_gemm128_ln<<<dim3(128, 8), 256, 0, stream>>>(bufA, W2t, bufB, g1, b1, partA, partB, 1024, 1024);
  k_gemm128_ln<<<dim3(128, 8), 256, 0, stream>>>(bufB, W3t, bufA, g2, b2, partB, partA, 1024, 1024);
  k_gemm128_ln<<<dim3(128, 8), 256, 0, stream>>>(bufA, W4t, bufB, g3, b3, partA, partB, 1024, 1024);
  k_gemm_sm<<<256, 256, 0, stream>>>(bufB, W5t, g4, b4, partB, b5, z, ep, sm);
  k_gemm256_div<<<dim3(64, 4), 512, 0, stream>>>(ep, logE, part_val, part_idx, 1024, 256);
  k_final<<<4096, 256, 0, stream>>>(part_val, part_idx, z, sm, emb, masks, q, blockloss);
  k_loss_reduce<<<1, 256, 0, stream>>>(blockloss, lossp);
}

// Round 19
// 241.958 us; speedup vs baseline: 1.1042x; 1.1042x over previous
//
#include <hip/hip_runtime.h>
#include <hip/hip_fp16.h>
#include <stdint.h>

typedef __attribute__((ext_vector_type(4))) float f32x4;
typedef __attribute__((ext_vector_type(2))) float f32x2;
typedef _Float16 f16;
typedef __attribute__((ext_vector_type(8))) _Float16 f16x8;
typedef __attribute__((ext_vector_type(4))) _Float16 f16x4;

#define LN_EPS 1e-5f

// ---------------- helpers ----------------
__device__ __forceinline__ void gload_lds16(const void* g, void* l) {
  __builtin_amdgcn_global_load_lds(
      (__attribute__((address_space(1))) void*)(uintptr_t)g,
      (__attribute__((address_space(3))) void*)(uint32_t)(uintptr_t)l,
      16, 0, 0);
}

__device__ __forceinline__ f32x4 mfma16(f16x8 a, f16x8 b, f32x4 c) {
  return __builtin_amdgcn_mfma_f32_16x16x32_f16(a, b, c, 0, 0, 0);
}

// ---------------- prep megakernel (weights + logE) ----------------
__device__ __forceinline__ void transpose256(const float* __restrict__ W,
                                             f16* __restrict__ Wt, int K, int N,
                                             int nt, int kt, float (*t)[33]) {
  int tx = threadIdx.x & 31;
  int ty0 = (threadIdx.x >> 5) * 4;
#pragma unroll
  for (int j = 0; j < 4; ++j)
    t[ty0 + j][tx] = W[(size_t)(kt + ty0 + j) * N + nt + tx];
  __syncthreads();
#pragma unroll
  for (int j = 0; j < 4; ++j)
    Wt[(size_t)(nt + ty0 + j) * K + kt + tx] = (f16)t[tx][ty0 + j];
}

__global__ __launch_bounds__(256) void k_prep(
    const float* __restrict__ W1, f16* __restrict__ W1t,
    const float* __restrict__ W2, f16* __restrict__ W2t,
    const float* __restrict__ W3, f16* __restrict__ W3t,
    const float* __restrict__ W4, f16* __restrict__ W4t,
    const float* __restrict__ W5, f16* __restrict__ W5t,
    const float* __restrict__ emb, f16* __restrict__ logE) {
  __shared__ float t[32][33];
  const int b = blockIdx.x;
  if (b < 512) {
    transpose256(W1, W1t, 512, 1024, (b & 31) * 32, (b >> 5) * 32, t);
  } else if (b < 3584) {
    int b3 = b - 512;
    int z = b3 >> 10;
    int b4 = b3 & 1023;
    const float* W = z == 0 ? W2 : (z == 1 ? W3 : W4);
    f16* T = z == 0 ? W2t : (z == 1 ? W3t : W4t);
    transpose256(W, T, 1024, 1024, (b4 & 31) * 32, (b4 >> 5) * 32, t);
  } else if (b < 3840) {
    int b5 = b - 3584;
    transpose256(W5, W5t, 1024, 256, (b5 & 7) * 32, (b5 >> 3) * 32, t);
  } else {
    int i = (b - 3840) * 256 + threadIdx.x;
    logE[i] = (f16)logf(emb[i] * 256.0f);  // argmax-invariant *256 shift
  }
}

// ============ shared pieces ============
__device__ __forceinline__ void stats_epilogue(char* lds, f32x4 (&acc)[8][4],
                                               f32x2* __restrict__ outPart,
                                               int bm0) {
  const int tid = threadIdx.x;
  const int lane = tid & 63;
  const int wid = tid >> 6;
  const int wm = wid >> 2, wn = wid & 3;
  const int r0 = (lane >> 4) * 4;
  const int cc = lane & 15;
  __builtin_amdgcn_s_barrier();
  float* stp = (float*)lds;
  float* stq = (float*)(lds + 4096);
#pragma unroll
  for (int mi = 0; mi < 8; ++mi) {
#pragma unroll
    for (int j = 0; j < 4; ++j) {
      float s = 0.f, q = 0.f;
#pragma unroll
      for (int ni = 0; ni < 4; ++ni) {
        float v = acc[mi][ni][j];
        s += v; q += v * v;
      }
#pragma unroll
      for (int d = 1; d < 16; d <<= 1) { s += __shfl_xor(s, d); q += __shfl_xor(q, d); }
      if (cc == 0) {
        int rl = wm * 128 + mi * 16 + r0 + j;
        stp[rl * 4 + wn] = s;
        stq[rl * 4 + wn] = q;
      }
    }
  }
  __syncthreads();
  if (tid < 256) {
    float s = stp[tid * 4] + stp[tid * 4 + 1] + stp[tid * 4 + 2] + stp[tid * 4 + 3];
    float q = stq[tid * 4] + stq[tid * 4 + 1] + stq[tid * 4 + 2] + stq[tid * 4 + 3];
    f32x2 pr; pr[0] = s; pr[1] = q;
    outPart[(size_t)(bm0 + tid) * 4 + blockIdx.y] = pr;
  }
}

// ============ shared 256x256 GEMM core (plain A), 2-barrier/K-tile ============
__device__ __forceinline__ void gemm256_core(
    const f16* __restrict__ A, const f16* __restrict__ Bt,
    char* lds, int bm0, int bn0, int K, f32x4 (&acc)[8][4]) {
  const int tid = threadIdx.x;
  const int lane = tid & 63;
  const int wid = tid >> 6;
  const int wm = wid >> 2;
  const int wn = wid & 3;
  const int NT = K >> 6;

  const int slin = tid * 16;
  const int lrow = slin >> 7;
  const int scol = (slin & 127) ^ ((lrow & 7) << 4);
  const char* Ab = (const char*)A;
  const char* Bb = (const char*)Bt;
  const uint32_t rs = (uint32_t)K * 2;

  const int klo = (lane >> 4) * 16;
  const int sw = (lane & 7) << 4;
  const uint32_t kx0 = (uint32_t)(klo ^ sw);
  const uint32_t kx1 = (uint32_t)((64 + klo) ^ sw);
  const uint32_t abase = (uint32_t)(wm * 128 + (lane & 15)) * 128;
  const uint32_t bbase = (uint32_t)(wn * 64 + (lane & 15)) * 128;

#pragma unroll
  for (int i = 0; i < 8; ++i)
#pragma unroll
    for (int j = 0; j < 4; ++j) acc[i][j] = 0.0f;

#define LDSA(buf) (lds + (buf)*32768)
#define LDSB(buf) (lds + 65536 + (buf)*32768)
#define STAGE_A(t, h)                                                              \
  {                                                                                \
    const char* src = Ab + (size_t)(bm0 + (h)*128 + lrow) * rs + ((t) << 7) + scol;\
    char* dst = LDSA((t)&1) + (h)*16384 + slin;                                    \
    gload_lds16(src, dst);                                                         \
    gload_lds16(src + (size_t)64 * rs, dst + 8192);                                \
  }
#define STAGE_B(t, h)                                                              \
  {                                                                                \
    const char* src = Bb + (size_t)(bn0 + (h)*128 + lrow) * rs + ((t) << 7) + scol;\
    char* dst = LDSB((t)&1) + (h)*16384 + slin;                                    \
    gload_lds16(src, dst);                                                         \
    gload_lds16(src + (size_t)64 * rs, dst + 8192);                                \
  }
#define HALF1(Acur, Bcur)                                                          \
  _Pragma("unroll") for (int ni = 0; ni < 4; ++ni) {                               \
    bF[ni][0] = *(const f16x8*)((Bcur) + bbase + ni * 2048 + kx0);                 \
    bF[ni][1] = *(const f16x8*)((Bcur) + bbase + ni * 2048 + kx1);                 \
  }                                                                                \
  {                                                                                \
    f16x8 aF[4][2];                                                                \
    _Pragma("unroll") for (int mi = 0; mi < 4; ++mi) {                             \
      aF[mi][0] = *(const f16x8*)((Acur) + abase + mi * 2048 + kx0);               \
      aF[mi][1] = *(const f16x8*)((Acur) + abase + mi * 2048 + kx1);               \
    }                                                                              \
    __builtin_amdgcn_s_setprio(1);                                                 \
    _Pragma("unroll") for (int mi = 0; mi < 4; ++mi)                               \
        _Pragma("unroll") for (int ni = 0; ni < 4; ++ni) {                         \
          acc[mi][ni] = mfma16(aF[mi][0], bF[ni][0], acc[mi][ni]);                 \
          acc[mi][ni] = mfma16(aF[mi][1], bF[ni][1], acc[mi][ni]);                 \
        }                                                                          \
    __builtin_amdgcn_s_setprio(0);                                                 \
  }
#define HALF2(Acur)                                                                \
  {                                                                                \
    f16x8 aF[4][2];                                                                \
    _Pragma("unroll") for (int mi = 0; mi < 4; ++mi) {                             \
      aF[mi][0] = *(const f16x8*)((Acur) + abase + (mi + 4) * 2048 + kx0);         \
      aF[mi][1] = *(const f16x8*)((Acur) + abase + (mi + 4) * 2048 + kx1);         \
    }                                                                              \
    __builtin_amdgcn_s_setprio(1);                                                 \
    _Pragma("unroll") for (int mi = 0; mi < 4; ++mi)                               \
        _Pragma("unroll") for (int ni = 0; ni < 4; ++ni) {                         \
          acc[mi + 4][ni] = mfma16(aF[mi][0], bF[ni][0], acc[mi + 4][ni]);         \
          acc[mi + 4][ni] = mfma16(aF[mi][1], bF[ni][1], acc[mi + 4][ni]);         \
        }                                                                          \
    __builtin_amdgcn_s_setprio(0);                                                 \
  }

  STAGE_A(0, 0); STAGE_A(0, 1); STAGE_B(0, 0); STAGE_B(0, 1);
  STAGE_B(1, 0); STAGE_B(1, 1);
  asm volatile("s_waitcnt vmcnt(4)");
  __builtin_amdgcn_s_barrier();
  __builtin_amdgcn_sched_barrier(0);

  f16x8 bF[4][2];
  for (int t = 0; t < NT - 2; ++t) {
    const char* Acur = LDSA(t & 1);
    const char* Bcur = LDSB(t & 1);
    STAGE_A(t + 1, 0); STAGE_A(t + 1, 1);
    HALF1(Acur, Bcur)
    __builtin_amdgcn_s_barrier();
    __builtin_amdgcn_sched_barrier(0);
    STAGE_B(t + 2, 0); STAGE_B(t + 2, 1);
    HALF2(Acur)
    asm volatile("s_waitcnt vmcnt(4)");
    __builtin_amdgcn_s_barrier();
    __builtin_amdgcn_sched_barrier(0);
  }
  {
    const char* Acur = LDSA((NT - 2) & 1);
    const char* Bcur = LDSB((NT - 2) & 1);
    STAGE_A(NT - 1, 0); STAGE_A(NT - 1, 1);
    HALF1(Acur, Bcur)
    __builtin_amdgcn_s_barrier();
    __builtin_amdgcn_sched_barrier(0);
    HALF2(Acur)
    asm volatile("s_waitcnt vmcnt(0)");
    __builtin_amdgcn_s_barrier();
    __builtin_amdgcn_sched_barrier(0);
  }
  {
    const char* Acur = LDSA((NT - 1) & 1);
    const char* Bcur = LDSB((NT - 1) & 1);
    HALF1(Acur, Bcur)
    HALF2(Acur)
  }
#undef STAGE_A
#undef HALF1
#undef HALF2
#undef LDSA
#undef LDSB
#undef STAGE_B
}

// ---- div-GEMM: per-row argmax partials over 64-col chunks ----
__global__ __launch_bounds__(512, 2) void k_gemm256_div(
    const f16* __restrict__ A, const f16* __restrict__ Bt,
    float* __restrict__ part_val, int* __restrict__ part_idx, int N, int K) {
  __shared__ char lds[131072];
  const int bm0 = blockIdx.x * 256;
  const int bn0 = blockIdx.y * 256;
  f32x4 acc[8][4];
  gemm256_core(A, Bt, lds, bm0, bn0, K, acc);

  const int lane = threadIdx.x & 63;
  const int wid = threadIdx.x >> 6;
  const int wm = wid >> 2, wn = wid & 3;
  const int r0 = (lane >> 4) * 4;
  const int cc = lane & 15;
  const int nch = N >> 6;
  const int chunk = (bn0 >> 6) + wn;
#pragma unroll
  for (int mi = 0; mi < 8; ++mi) {
#pragma unroll
    for (int j = 0; j < 4; ++j) {
      float v = acc[mi][0][j];
      int c = cc;
#pragma unroll
      for (int ni = 1; ni < 4; ++ni) {
        float v2 = acc[mi][ni][j];
        int c2 = ni * 16 + cc;
        if (v2 > v) { v = v2; c = c2; }
      }
#pragma unroll
      for (int d = 1; d < 16; d <<= 1) {
        float ov = __shfl_xor(v, d);
        int oc = __shfl_xor(c, d);
        if (ov > v || (ov == v && oc < c)) { v = ov; c = oc; }
      }
      if (cc == 0) {
        int r = bm0 + wm * 128 + mi * 16 + r0 + j;
        part_val[r * nch + chunk] = v;
        part_idx[r * nch + chunk] = bn0 + wn * 64 + c;
      }
    }
  }
}

// ---- L1: A = x (f32), fused cvt in A-stage; stats epilogue; h store ----
__global__ __launch_bounds__(512, 2) void k_gemm256_cvt(
    const float* __restrict__ A, const f16* __restrict__ Bt,
    f16* __restrict__ O, f32x2* __restrict__ outPart, int N, int K) {
  __shared__ char lds[131072];
  const int tid = threadIdx.x;
  const int lane = tid & 63;
  const int wid = tid >> 6;
  const int wm = wid >> 2;
  const int wn = wid & 3;
  const int bm0 = blockIdx.x * 256;
  const int bn0 = blockIdx.y * 256;
  const int NT = K >> 6;

  const int slin = tid * 16;
  const int lrow = slin >> 7;
  const int scol = (slin & 127) ^ ((lrow & 7) << 4);
  const char* Ab = (const char*)A;        // f32, row stride K*4
  const char* Bb = (const char*)Bt;
  const uint32_t rsA = (uint32_t)K * 4;
  const uint32_t rs = (uint32_t)K * 2;

  const int klo = (lane >> 4) * 16;
  const int sw = (lane & 7) << 4;
  const uint32_t kx0 = (uint32_t)(klo ^ sw);
  const uint32_t kx1 = (uint32_t)((64 + klo) ^ sw);
  const uint32_t abase = (uint32_t)(wm * 128 + (lane & 15)) * 128;
  const uint32_t bbase = (uint32_t)(wn * 64 + (lane & 15)) * 128;

  const int alrow = tid >> 3;
  const uint32_t acolbF = (uint32_t)(tid & 7) * 32;
  const uint32_t awcol = ((uint32_t)(tid & 7) * 16) ^ (uint32_t)((alrow & 7) << 4);
  f32x4 arf[4][2];

  f32x4 acc[8][4];
#pragma unroll
  for (int i = 0; i < 8; ++i)
#pragma unroll
    for (int j = 0; j < 4; ++j) acc[i][j] = 0.0f;

#define LDSA(buf) (lds + (buf)*32768)
#define LDSB(buf) (lds + 65536 + (buf)*32768)
#define STAGE_B(t, h)                                                              \
  {                                                                                \
    const char* src = Bb + (size_t)(bn0 + (h)*128 + lrow) * rs + ((t) << 7) + scol;\
    char* dst = LDSB((t)&1) + (h)*16384 + slin;                                    \
    gload_lds16(src, dst);                                                         \
    gload_lds16(src + (size_t)64 * rs, dst + 8192);                                \
  }
#define A_ISSUE(t1)                                                               \
  {                                                                               \
    const char* base_ = Ab + (size_t)(bm0 + alrow) * rsA + ((size_t)(t1) << 8) + acolbF; \
    _Pragma("unroll") for (int i = 0; i < 4; ++i) {                               \
      arf[i][0] = *(const f32x4*)(base_ + (size_t)(i * 64) * rsA);                \
      arf[i][1] = *(const f32x4*)(base_ + (size_t)(i * 64) * rsA + 16);           \
    }                                                                             \
  }
#define A_WRITE(t1)                                                               \
  {                                                                               \
    char* wb_ = LDSA((t1)&1);                                                     \
    _Pragma("unroll") for (int i = 0; i < 4; ++i) {                               \
      f16x8 o;                                                                    \
      _Pragma("unroll") for (int e = 0; e < 4; ++e) {                             \
        o[e] = (f16)arf[i][0][e];                                                 \
        o[e + 4] = (f16)arf[i][1][e];                                             \
      }                                                                           \
      *(f16x8*)(wb_ + (i >> 1) * 16384 + (alrow + (i & 1) * 64) * 128 + awcol) = o; \
    }                                                                             \
  }
#define HALF1(Acur, Bcur)                                                          \
  _Pragma("unroll") for (int ni = 0; ni < 4; ++ni) {                               \
    bF[ni][0] = *(const f16x8*)((Bcur) + bbase + ni * 2048 + kx0);                 \
    bF[ni][1] = *(const f16x8*)((Bcur) + bbase + ni * 2048 + kx1);                 \
  }                                                                                \
  {                                                                                \
    f16x8 aF[4][2];                                                                \
    _Pragma("unroll") for (int mi = 0; mi < 4; ++mi) {                             \
      aF[mi][0] = *(const f16x8*)((Acur) + abase + mi * 2048 + kx0);               \
      aF[mi][1] = *(const f16x8*)((Acur) + abase + mi * 2048 + kx1);               \
    }                                                                              \
    __builtin_amdgcn_s_setprio(1);                                                 \
    _Pragma("unroll") for (int mi = 0; mi < 4; ++mi)                               \
        _Pragma("unroll") for (int ni = 0; ni < 4; ++ni) {                         \
          acc[mi][ni] = mfma16(aF[mi][0], bF[ni][0], acc[mi][ni]);                 \
          acc[mi][ni] = mfma16(aF[mi][1], bF[ni][1], acc[mi][ni]);                 \
        }                                                                          \
    __builtin_amdgcn_s_setprio(0);                                                 \
  }
#define HALF2(Acur)                                                                \
  {                                                                                \
    f16x8 aF[4][2];                                                                \
    _Pragma("unroll") for (int mi = 0; mi < 4; ++mi) {                             \
      aF[mi][0] = *(const f16x8*)((Acur) + abase + (mi + 4) * 2048 + kx0);         \
      aF[mi][1] = *(const f16x8*)((Acur) + abase + (mi + 4) * 2048 + kx1);         \
    }                                                                              \
    __builtin_amdgcn_s_setprio(1);                                                 \
    _Pragma("unroll") for (int mi = 0; mi < 4; ++mi)                               \
        _Pragma("unroll") for (int ni = 0; ni < 4; ++ni) {                         \
          acc[mi + 4][ni] = mfma16(aF[mi][0], bF[ni][0], acc[mi + 4][ni]);         \
          acc[mi + 4][ni] = mfma16(aF[mi][1], bF[ni][1], acc[mi + 4][ni]);         \
        }                                                                          \
    __builtin_amdgcn_s_setprio(0);                                                 \
  }

  A_ISSUE(0)
  STAGE_B(0, 0); STAGE_B(0, 1); STAGE_B(1, 0); STAGE_B(1, 1);
  asm volatile("s_waitcnt vmcnt(8)");
  A_WRITE(0)
  asm volatile("s_waitcnt vmcnt(4) lgkmcnt(0)");
  __builtin_amdgcn_s_barrier();
  __builtin_amdgcn_sched_barrier(0);

  f16x8 bF[4][2];
  for (int t = 0; t < NT - 2; ++t) {
    const char* Acur = LDSA(t & 1);
    const char* Bcur = LDSB(t & 1);
    A_ISSUE(t + 1)
    HALF1(Acur, Bcur)
    __builtin_amdgcn_s_barrier();
    __builtin_amdgcn_sched_barrier(0);
    STAGE_B(t + 2, 0); STAGE_B(t + 2, 1);
    HALF2(Acur)
    asm volatile("s_waitcnt vmcnt(4)");
    A_WRITE(t + 1)
    asm volatile("s_waitcnt lgkmcnt(0)");
    __builtin_amdgcn_s_barrier();
    __builtin_amdgcn_sched_barrier(0);
  }
  {
    const char* Acur = LDSA((NT - 2) & 1);
    const char* Bcur = LDSB((NT - 2) & 1);
    A_ISSUE(NT - 1)
    HALF1(Acur, Bcur)
    __builtin_amdgcn_s_barrier();
    __builtin_amdgcn_sched_barrier(0);
    HALF2(Acur)
    asm volatile("s_waitcnt vmcnt(0)");
    A_WRITE(NT - 1)
    asm volatile("s_waitcnt lgkmcnt(0)");
    __builtin_amdgcn_s_barrier();
    __builtin_amdgcn_sched_barrier(0);
  }
  {
    const char* Acur = LDSA((NT - 1) & 1);
    const char* Bcur = LDSB((NT - 1) & 1);
    HALF1(Acur, Bcur)
    HALF2(Acur)
  }
#undef STAGE_B
#undef A_ISSUE
#undef A_WRITE
#undef HALF1
#undef HALF2
#undef LDSA
#undef LDSB

  stats_epilogue(lds, acc, outPart, bm0);

  const int r0 = (lane >> 4) * 4;
  const int cc = lane & 15;
#pragma unroll
  for (int mi = 0; mi < 8; ++mi) {
#pragma unroll
    for (int ni = 0; ni < 4; ++ni) {
      int r = bm0 + wm * 128 + mi * 16 + r0;
      int c = bn0 + wn * 64 + ni * 16 + cc;
#pragma unroll
      for (int j = 0; j < 4; ++j)
        O[(size_t)(r + j) * N + c] = (f16)acc[mi][ni][j];
    }
  }
}

// ======== consumer-LN fused GEMM + stats (L2/L3/L4), packed-f16 transform ========
__global__ __launch_bounds__(512, 2) void k_gemm256_ln(
    const f16* __restrict__ A, const f16* __restrict__ Bt,
    f16* __restrict__ O, const float* __restrict__ gw,
    const float* __restrict__ bw, const f32x2* __restrict__ inPart,
    f32x2* __restrict__ outPart, int N, int K) {
  __shared__ char lds[135168];  // A dbuf 2x32K @0, B dbuf 2x32K @65536, g/b 4K @131072
  const int GB = 131072;
  const int tid = threadIdx.x;
  const int lane = tid & 63;
  const int wid = tid >> 6;
  const int wm = wid >> 2;
  const int wn = wid & 3;
  const int bm0 = blockIdx.x * 256;
  const int bn0 = blockIdx.y * 256;
  const int NT = K >> 6;

  const int slin = tid * 16;
  const int lrow = slin >> 7;
  const int scol = (slin & 127) ^ ((lrow & 7) << 4);
  const char* Ab = (const char*)A;
  const char* Bb = (const char*)Bt;
  const uint32_t rs = (uint32_t)K * 2;

  const int klo = (lane >> 4) * 16;
  const int sw = (lane & 7) << 4;
  const uint32_t kx0 = (uint32_t)(klo ^ sw);
  const uint32_t kx1 = (uint32_t)((64 + klo) ^ sw);
  const uint32_t abase = (uint32_t)(wm * 128 + (lane & 15)) * 128;
  const uint32_t bbase = (uint32_t)(wn * 64 + (lane & 15)) * 128;

  const int alrow = tid >> 3;
  const uint32_t acolb = (uint32_t)(tid & 7) * 16;
  const uint32_t awcol = acolb ^ (uint32_t)((alrow & 7) << 4);
  f16 aSh[4], cSh[4];
  f16x8 ar[4];

  f32x4 acc[8][4];
#pragma unroll
  for (int i = 0; i < 8; ++i)
#pragma unroll
    for (int j = 0; j < 4; ++j) acc[i][j] = 0.0f;

#define LDSA(buf) (lds + (buf)*32768)
#define LDSB(buf) (lds + 65536 + (buf)*32768)
#define STAGE_B(t, h)                                                              \
  {                                                                                \
    const char* src = Bb + (size_t)(bn0 + (h)*128 + lrow) * rs + ((t) << 7) + scol;\
    char* dst = LDSB((t)&1) + (h)*16384 + slin;                                    \
    gload_lds16(src, dst);                                                         \
    gload_lds16(src + (size_t)64 * rs, dst + 8192);                                \
  }
#define A_ISSUE(t1)                                                               \
  {                                                                               \
    const char* base_ = Ab + (size_t)(bm0 + alrow) * rs + ((size_t)(t1) << 7) + acolb; \
    ar[0] = *(const f16x8*)(base_);                                               \
    ar[1] = *(const f16x8*)(base_ + (size_t)64 * rs);                             \
    ar[2] = *(const f16x8*)(base_ + (size_t)128 * rs);                            \
    ar[3] = *(const f16x8*)(base_ + (size_t)192 * rs);                            \
  }
// packed transform via ext-vector math: a' = relu((a*rstd + (-mu*rstd))*g + b)
#define A_WRITE(t1)                                                               \
  {                                                                               \
    uint32_t off_ = GB + (uint32_t)(t1)*128 + (uint32_t)(tid & 7) * 16;           \
    f16x8 gr = *(const f16x8*)(lds + off_);                                       \
    f16x8 br = *(const f16x8*)(lds + off_ + 2048);                                \
    char* wb_ = LDSA((t1)&1);                                                     \
    _Pragma("unroll") for (int i = 0; i < 4; ++i) {                               \
      f16x8 aS8, cS8, zz;                                                         \
      _Pragma("unroll") for (int p = 0; p < 8; ++p) {                             \
        aS8[p] = aSh[i]; cS8[p] = cSh[i]; zz[p] = (f16)0.f;                       \
      }                                                                           \
      f16x8 tt = ar[i] * aS8 + cS8;                                               \
      tt = tt * gr + br;                                                          \
      tt = __builtin_elementwise_max(tt, zz);                                     \
      *(f16x8*)(wb_ + (i >> 1) * 16384 + (alrow + (i & 1) * 64) * 128 + awcol) = tt; \
    }                                                                             \
  }

  // prologue: g/b -> LDS as f16; stats from partials; A(0) regs + B(0),B(1)
  if (tid < 256) {
    f32x4 g4 = ((const f32x4*)gw)[tid];
    f32x4 b4 = ((const f32x4*)bw)[tid];
    f16x4 gh, bh;
#pragma unroll
    for (int e = 0; e < 4; ++e) { gh[e] = (f16)g4[e]; bh[e] = (f16)b4[e]; }
    ((f16x4*)(lds + GB))[tid] = gh;
    ((f16x4*)(lds + GB + 2048))[tid] = bh;
  }
#pragma unroll
  for (int i = 0; i < 4; ++i) {
    int r = bm0 + (i >> 1) * 128 + (i & 1) * 64 + alrow;
    const f32x4* pp = (const f32x4*)(inPart + (size_t)r * 4);
    f32x4 p0 = pp[0], p1 = pp[1];
    float s = p0[0] + p0[2] + p1[0] + p1[2];
    float q = p0[1] + p0[3] + p1[1] + p1[3];
    float mu = s * (1.0f / 1024.0f);
    float var = q * (1.0f / 1024.0f) - mu * mu;
    float rstd = rsqrtf(var + LN_EPS);
    aSh[i] = (f16)rstd;
    cSh[i] = (f16)(-mu * rstd);
  }
  __builtin_amdgcn_sched_barrier(0);
  A_ISSUE(0)
  STAGE_B(0, 0); STAGE_B(0, 1); STAGE_B(1, 0); STAGE_B(1, 1);
  __builtin_amdgcn_sched_barrier(0);
  asm volatile("s_waitcnt lgkmcnt(0)");
  __builtin_amdgcn_s_barrier();               // g/b visible to all waves
  asm volatile("s_waitcnt vmcnt(8)");          // ar(0) landed
  A_WRITE(0)
  asm volatile("s_waitcnt vmcnt(4) lgkmcnt(0)");  // B(0) landed, A(0) written
  __builtin_amdgcn_s_barrier();
  __builtin_amdgcn_sched_barrier(0);

  for (int t = 0; t < NT; ++t) {
    const char* Acur = LDSA(t & 1);
    const char* Bcur = LDSB(t & 1);

    if (t + 1 < NT) { A_ISSUE(t + 1) }
    f16x8 bF[4][2];
#pragma unroll
    for (int ni = 0; ni < 4; ++ni) {
      bF[ni][0] = *(const f16x8*)(Bcur + bbase + ni * 2048 + kx0);
      bF[ni][1] = *(const f16x8*)(Bcur + bbase + ni * 2048 + kx1);
    }
    {
      f16x8 aF[4][2];
#pragma unroll
      for (int mi = 0; mi < 4; ++mi) {
        aF[mi][0] = *(const f16x8*)(Acur + abase + mi * 2048 + kx0);
        aF[mi][1] = *(const f16x8*)(Acur + abase + mi * 2048 + kx1);
      }
      __builtin_amdgcn_s_setprio(1);
#pragma unroll
      for (int mi = 0; mi < 4; ++mi)
#pragma unroll
        for (int ni = 0; ni < 4; ++ni) {
          acc[mi][ni] = mfma16(aF[mi][0], bF[ni][0], acc[mi][ni]);
          acc[mi][ni] = mfma16(aF[mi][1], bF[ni][1], acc[mi][ni]);
        }
      __builtin_amdgcn_s_setprio(0);
    }
    __builtin_amdgcn_s_barrier();
    __builtin_amdgcn_sched_barrier(0);

    if (t + 2 < NT) { STAGE_B(t + 2, 0); STAGE_B(t + 2, 1); }
    {
      f16x8 aF[4][2];
#pragma unroll
      for (int mi = 0; mi < 4; ++mi) {
        aF[mi][0] = *(const f16x8*)(Acur + abase + (mi + 4) * 2048 + kx0);
        aF[mi][1] = *(const f16x8*)(Acur + abase + (mi + 4) * 2048 + kx1);
      }
      __builtin_amdgcn_s_setprio(1);
#pragma unroll
      for (int mi = 0; mi < 4; ++mi)
#pragma unroll
        for (int ni = 0; ni < 4; ++ni) {
          acc[mi + 4][ni] = mfma16(aF[mi][0], bF[ni][0], acc[mi + 4][ni]);
          acc[mi + 4][ni] = mfma16(aF[mi][1], bF[ni][1], acc[mi + 4][ni]);
        }
      __builtin_amdgcn_s_setprio(0);
    }
    if (t + 1 < NT) {
      if (t + 2 < NT) { asm volatile("s_waitcnt vmcnt(4)"); }
      else            { asm volatile("s_waitcnt vmcnt(0)"); }
      A_WRITE(t + 1)
      asm volatile("s_waitcnt lgkmcnt(0)");
      __builtin_amdgcn_s_barrier();
      __builtin_amdgcn_sched_barrier(0);
    }
  }
#undef STAGE_B
#undef A_ISSUE
#undef A_WRITE
#undef LDSA
#undef LDSB

  stats_epilogue(lds, acc, outPart, bm0);

  const int r0 = (lane >> 4) * 4;
  const int cc = lane & 15;
#pragma unroll
  for (int mi = 0; mi < 8; ++mi) {
#pragma unroll
    for (int ni = 0; ni < 4; ++ni) {
      int r = bm0 + wm * 128 + mi * 16 + r0;
      int c = bn0 + wn * 64 + ni * 16 + cc;
#pragma unroll
      for (int j = 0; j < 4; ++j)
        O[(size_t)(r + j) * N + c] = (f16)acc[mi][ni][j];
    }
  }
}

// ======== fused LN(h4) -> G5 -> softmax, pipelined B dbuf, packed-f16 ========
__global__ __launch_bounds__(256) void k_gemm_sm(
    const f16* __restrict__ A, const f16* __restrict__ Bt,
    const float* __restrict__ gw, const float* __restrict__ bw,
    const f32x2* __restrict__ inPart, const float* __restrict__ bias,
    float* __restrict__ z, f16* __restrict__ ep, float* __restrict__ sm) {
  const int K = 1024;
  __shared__ char lds[77824];  // A 8K @0, B dbuf 2x32K @8192, g/b 4K @73728
  const int GBS = 73728;
  char* ldsA = lds;
  const int tid = threadIdx.x;
  const int lane = tid & 63;
  const int wn = tid >> 6;
  const int bm0 = blockIdx.x * 64;
  const char* Ab = (const char*)A;
  const char* Bb = (const char*)Bt;
  const uint32_t rs = (uint32_t)K * 2;
  const int cc = lane & 15;

  {
    f32x4 g4 = ((const f32x4*)gw)[tid];
    f32x4 b4 = ((const f32x4*)bw)[tid];
    f16x4 gh, bh;
#pragma unroll
    for (int e = 0; e < 4; ++e) { gh[e] = (f16)g4[e]; bh[e] = (f16)b4[e]; }
    ((f16x4*)(lds + GBS))[tid] = gh;
    ((f16x4*)(lds + GBS + 2048))[tid] = bh;
  }

  const int ar0 = tid >> 3;
  f16 aSh[2], cSh[2];
#pragma unroll
  for (int i = 0; i < 2; ++i) {
    int r = bm0 + ar0 + i * 32;
    const f32x4* pp = (const f32x4*)(inPart + (size_t)r * 4);
    f32x4 p0 = pp[0], p1 = pp[1];
    float s = p0[0] + p0[2] + p1[0] + p1[2];
    float q = p0[1] + p0[3] + p1[1] + p1[3];
    float mu = s * (1.0f / 1024.0f);
    float var = q * (1.0f / 1024.0f) - mu * mu;
    float rstd = rsqrtf(var + LN_EPS);
    aSh[i] = (f16)rstd;
    cSh[i] = (f16)(-mu * rstd);
  }
  const uint32_t acolb = (uint32_t)(tid & 7) * 16;
  const uint32_t awcol = acolb ^ (uint32_t)((ar0 & 7) << 4);

  uint32_t ra[2][4], rb[2][4];
  {
    const int sww = (lane & 7) << 4;
    const int gk = lane & 48;
#pragma unroll
    for (int kk = 0; kk < 2; ++kk) {
#pragma unroll
      for (int i = 0; i < 4; ++i) {
        uint32_t kb = (uint32_t)((kk * 64 + gk) ^ sww);
        ra[kk][i] = (uint32_t)(i * 16 + cc) * 128 + kb;
        rb[kk][i] = (uint32_t)(wn * 64 + i * 16 + cc) * 128 + kb;
      }
    }
  }

  f32x4 acc[4][4];
#pragma unroll
  for (int i = 0; i < 4; ++i)
#pragma unroll
    for (int j = 0; j < 4; ++j) acc[i][j] = 0.0f;

#define STAGE_BS(t)                                                               \
  {                                                                               \
    char* bdst = lds + 8192 + ((t)&1) * 32768;                                    \
    _Pragma("unroll") for (int i = 0; i < 8; ++i) {                               \
      int lin = i * 4096 + tid * 16;                                              \
      int row = lin >> 7;                                                         \
      int col = (lin & 127) ^ ((row & 7) << 4);                                   \
      gload_lds16(Bb + (size_t)row * rs + ((size_t)(t) << 7) + col, bdst + lin);  \
    }                                                                             \
  }

  STAGE_BS(0)
  asm volatile("s_waitcnt lgkmcnt(0)");
  __builtin_amdgcn_s_barrier();   // g/b visible
  __builtin_amdgcn_sched_barrier(0);

  for (int t = 0; t < 16; ++t) {
    const char* abase_ = Ab + (size_t)(bm0 + ar0) * rs + ((size_t)t << 7) + acolb;
    f16x8 a0 = *(const f16x8*)abase_;
    f16x8 a1 = *(const f16x8*)(abase_ + (size_t)32 * rs);
    if (t + 1 < 16) { STAGE_BS(t + 1) }
    if (t + 1 < 16) { asm volatile("s_waitcnt vmcnt(8)"); }  // drains B(t)+a0,a1
    else            { asm volatile("s_waitcnt vmcnt(0)"); }
    {
      uint32_t off_ = GBS + (uint32_t)t * 128 + (uint32_t)(tid & 7) * 16;
      f16x8 gr = *(const f16x8*)(lds + off_);
      f16x8 br = *(const f16x8*)(lds + off_ + 2048);
      f16x8 aS0, cS0, aS1, cS1, zz;
#pragma unroll
      for (int p = 0; p < 8; ++p) {
        aS0[p] = aSh[0]; cS0[p] = cSh[0];
        aS1[p] = aSh[1]; cS1[p] = cSh[1];
        zz[p] = (f16)0.f;
      }
      f16x8 t0 = a0 * aS0 + cS0;
      f16x8 t1 = a1 * aS1 + cS1;
      t0 = t0 * gr + br;
      t1 = t1 * gr + br;
      t0 = __builtin_elementwise_max(t0, zz);
      t1 = __builtin_elementwise_max(t1, zz);
      *(f16x8*)(ldsA + ar0 * 128 + awcol) = t0;
      *(f16x8*)(ldsA + (ar0 + 32) * 128 + awcol) = t1;
    }
    asm volatile("s_waitcnt lgkmcnt(0)");
    __builtin_amdgcn_s_barrier();   // ldsA written by all; B(t) landed
    __builtin_amdgcn_sched_barrier(0);
    {
      const char* Bcur = lds + 8192 + (t & 1) * 32768;
#pragma unroll
      for (int kk = 0; kk < 2; ++kk) {
        f16x8 af[4], bfv[4];
#pragma unroll
        for (int i = 0; i < 4; ++i) af[i] = *(const f16x8*)(ldsA + ra[kk][i]);
#pragma unroll
        for (int i = 0; i < 4; ++i) bfv[i] = *(const f16x8*)(Bcur + rb[kk][i]);
#pragma unroll
        for (int mi = 0; mi < 4; ++mi)
#pragma unroll
          for (int ni = 0; ni < 4; ++ni)
            acc[mi][ni] = mfma16(af[mi], bfv[ni], acc[mi][ni]);
      }
    }
    __builtin_amdgcn_s_barrier();   // all reads of ldsA / B(t) done before overwrite
    __builtin_amdgcn_sched_barrier(0);
  }
#undef STAGE_BS

  // ---- softmax epilogue over full 256-wide rows ----
  __syncthreads();
  float* stm = (float*)lds;
  float* sts = (float*)(lds + 1024);
  float* rowm = (float*)(lds + 2048);
  float* rows_ = (float*)(lds + 2304);

  const int r0 = (lane >> 4) * 4;
  float bvv[4];
#pragma unroll
  for (int ni = 0; ni < 4; ++ni) bvv[ni] = bias[wn * 64 + ni * 16 + cc];

#pragma unroll
  for (int mi = 0; mi < 4; ++mi) {
#pragma unroll
    for (int j = 0; j < 4; ++j) {
      float m = -3.4e38f;
#pragma unroll
      for (int ni = 0; ni < 4; ++ni) m = fmaxf(m, acc[mi][ni][j] + bvv[ni]);
#pragma unroll
      for (int d = 1; d < 16; d <<= 1) m = fmaxf(m, __shfl_xor(m, d));
      if (cc == 0) stm[wn * 64 + mi * 16 + r0 + j] = m;
    }
  }
  __syncthreads();
  if (tid < 64) {
    float m = fmaxf(fmaxf(stm[tid], stm[64 + tid]), fmaxf(stm[128 + tid], stm[192 + tid]));
    rowm[tid] = m;
  }
  __syncthreads();
#pragma unroll
  for (int mi = 0; mi < 4; ++mi) {
#pragma unroll
    for (int j = 0; j < 4; ++j) {
      int r = mi * 16 + r0 + j;
      float m = rowm[r];
      float s = 0.f;
#pragma unroll
      for (int ni = 0; ni < 4; ++ni) s += expf(acc[mi][ni][j] + bvv[ni] - m);
#pragma unroll
      for (int d = 1; d < 16; d <<= 1) s += __shfl_xor(s, d);
      if (cc == 0) sts[wn * 64 + r] = s;
    }
  }
  __syncthreads();
  if (tid < 64) {
    float s = sts[tid] + sts[64 + tid] + sts[128 + tid] + sts[192 + tid];
    rows_[tid] = s;
    sm[bm0 + tid] = rowm[tid] + logf(s);
  }
  __syncthreads();
#pragma unroll
  for (int mi = 0; mi < 4; ++mi) {
#pragma unroll
    for (int j = 0; j < 4; ++j) {
      int r = mi * 16 + r0 + j;
      float m = rowm[r];
      float inv = 1.0f / rows_[r];
      float* zp = z + (size_t)(bm0 + r) * 256;
      f16* epp = ep + (size_t)(bm0 + r) * 256;
#pragma unroll
      for (int ni = 0; ni < 4; ++ni) {
        int c = wn * 64 + ni * 16 + cc;
        float zz = acc[mi][ni][j] + bvv[ni];
        zp[c] = zz;
        epp[c] = (f16)(expf(zz - m) * inv);
      }
    }
  }
}

// ---------------- finalize: argmax reduce, gather q, fp32 kl from z,sm ----------------
__global__ __launch_bounds__(256) void k_final(
    const float* __restrict__ part_val, const int* __restrict__ part_idx,
    const float* __restrict__ z, const float* __restrict__ sm,
    const float* __restrict__ emb, const float* __restrict__ masks,
    float* __restrict__ q, float* __restrict__ blockloss) {
  __shared__ float ls[4];
  int lane = threadIdx.x & 63;
  int w = threadIdx.x >> 6;
  int row = blockIdx.x * 4 + w;
  float v = -3.4e38f;
  int c = 0x7fffffff;
  if (lane < 16) { v = part_val[row * 16 + lane]; c = part_idx[row * 16 + lane]; }
#pragma unroll
  for (int d = 1; d < 16; d <<= 1) {
    float ov = __shfl_xor(v, d);
    int oc = __shfl_xor(c, d);
    if (ov > v || (ov == v && oc < c)) { v = ov; c = oc; }
  }
  int code = __shfl(c, 0);
  f32x4 ev = ((const f32x4*)(emb + (size_t)code * 256))[lane];
  ((f32x4*)(q + (size_t)row * 256))[lane] = ev;
  f32x4 zv = ((const f32x4*)(z + (size_t)row * 256))[lane];
  float smr = sm[row];
  float kl = 0.f;
#pragma unroll
  for (int j = 0; j < 4; ++j) {
    float pj = zv[j] - smr;
    kl += expf(pj) * (pj - logf(ev[j]));
  }
#pragma unroll
  for (int d = 1; d < 64; d <<= 1) kl += __shfl_xor(kl, d);
  if (lane == 0) ls[w] = kl * masks[row];
  __syncthreads();
  if (threadIdx.x == 0) blockloss[blockIdx.x] = ls[0] + ls[1] + ls[2] + ls[3];
}

__global__ __launch_bounds__(256) void k_loss_reduce(const float* __restrict__ bl,
                                                     float* __restrict__ out) {
  __shared__ float s[256];
  float a = 0.f;
#pragma unroll
  for (int i = 0; i < 16; ++i) a += bl[threadIdx.x + i * 256];
  s[threadIdx.x] = a;
  __syncthreads();
  for (int st = 128; st > 0; st >>= 1) {
    if (threadIdx.x < st) s[threadIdx.x] += s[threadIdx.x + st];
    __syncthreads();
  }
  if (threadIdx.x == 0) out[0] = s[0] * (0.25f / 16.0f);
}

// ---------------- launch ----------------
extern "C" void kernel_launch(void* const* d_in, const int* in_sizes, int n_in,
                              void* d_out, int out_size, void* d_ws, size_t ws_size,
                              hipStream_t stream) {
  const float* x = (const float*)d_in[0];
  const float* masks = (const float*)d_in[1];
  const float* W1 = (const float*)d_in[2];
  const float* g1 = (const float*)d_in[3];
  const float* b1 = (const float*)d_in[4];
  const float* W2 = (const float*)d_in[5];
  const float* g2 = (const float*)d_in[6];
  const float* b2 = (const float*)d_in[7];
  const float* W3 = (const float*)d_in[8];
  const float* g3 = (const float*)d_in[9];
  const float* b3 = (const float*)d_in[10];
  const float* W4 = (const float*)d_in[11];
  const float* g4 = (const float*)d_in[12];
  const float* b4 = (const float*)d_in[13];
  const float* W5 = (const float*)d_in[14];
  const float* b5 = (const float*)d_in[15];
  const float* emb = (const float*)d_in[16];

  const int M = 16384;  // B*T
  char* ws = (char*)d_ws;
  f16* bufA = (f16*)(ws);                       // 32 MB ping
  f16* bufB = (f16*)(ws + (32ull << 20));       // 32 MB pong
  f16* W1t = (f16*)(ws + (64ull << 20));        // 1 MB  [1024][512]
  f16* W2t = (f16*)(ws + (65ull << 20));        // 2 MB
  f16* W3t = (f16*)(ws + (67ull << 20));        // 2 MB
  f16* W4t = (f16*)(ws + (69ull << 20));        // 2 MB
  f16* W5t = (f16*)(ws + (71ull << 20));        // 0.5 MB [256][1024]
  f16* logE = (f16*)(ws + (72ull << 20));       // 0.5 MB [1024][256]
  float* part_val = (float*)(ws + (73ull << 20));     // 1 MB
  int* part_idx = (int*)(ws + (74ull << 20));         // 1 MB
  float* blockloss = (float*)(ws + (75ull << 20));    // 16 KB
  float* sm = (float*)(ws + (76ull << 20));           // 64 KB
  f32x2* partA = (f32x2*)(ws + (77ull << 20));        // 512 KB [16384][4]
  f32x2* partB = (f32x2*)(ws + (78ull << 20));        // 512 KB
  f16* ep = (f16*)(ws + (16ull << 20));               // 8 MB, aliases bufA upper half

  float* z = (float*)d_out;                 // [16384][256]
  float* q = z + (size_t)M * 256;           // [16384][256]
  float* lossp = z + 2ull * M * 256;        // [1]

  k_prep<<<4864, 256, 0, stream>>>(W1, W1t, W2, W2t, W3, W3t, W4, W4t,
                                   W5, W5t, emb, logE);
  k_gemm256_cvt<<<dim3(64, 4), 512, 0, stream>>>(x, W1t, bufA, partA, 1024, 512);
  k_gemm256_ln<<<dim3(64, 4), 512, 0, stream>>>(bufA, W2t, bufB, g1, b1, partA, partB, 1024, 1024);
  k_gemm256_ln<<<dim3(64, 4), 512, 0, stream>>>(bufB, W3t, bufA, g2, b2, partB, partA, 1024, 1024);
  k_gemm256_ln<<<dim3(64, 4), 512, 0, stream>>>(bufA, W4t, bufB, g3, b3, partA, partB, 1024, 1024);
  k_gemm_sm<<<256, 256, 0, stream>>>(bufB, W5t, g4, b4, partB, b5, z, ep, sm);
  k_gemm256_div<<<dim3(64, 4), 512, 0, stream>>>(ep, logE, part_val, part_idx, 1024, 256);
  k_final<<<4096, 256, 0, stream>>>(part_val, part_idx, z, sm, emb, masks, q, blockloss);
  k_loss_reduce<<<1, 256, 0, stream>>>(blockloss, lossp);
}

// Round 20
// 237.710 us; speedup vs baseline: 1.1240x; 1.0179x over previous
//
#include <hip/hip_runtime.h>
#include <hip/hip_fp16.h>
#include <stdint.h>

typedef __attribute__((ext_vector_type(4))) float f32x4;
typedef __attribute__((ext_vector_type(2))) float f32x2;
typedef _Float16 f16;
typedef __attribute__((ext_vector_type(8))) _Float16 f16x8;
typedef __attribute__((ext_vector_type(4))) _Float16 f16x4;

#define LN_EPS 1e-5f

// ---------------- helpers ----------------
__device__ __forceinline__ void gload_lds16(const void* g, void* l) {
  __builtin_amdgcn_global_load_lds(
      (__attribute__((address_space(1))) void*)(uintptr_t)g,
      (__attribute__((address_space(3))) void*)(uint32_t)(uintptr_t)l,
      16, 0, 0);
}

__device__ __forceinline__ f32x4 mfma16(f16x8 a, f16x8 b, f32x4 c) {
  return __builtin_amdgcn_mfma_f32_16x16x32_f16(a, b, c, 0, 0, 0);
}

// ---------------- prep megakernel (weights + logE) ----------------
__device__ __forceinline__ void transpose256(const float* __restrict__ W,
                                             f16* __restrict__ Wt, int K, int N,
                                             int nt, int kt, float (*t)[33]) {
  int tx = threadIdx.x & 31;
  int ty0 = (threadIdx.x >> 5) * 4;
#pragma unroll
  for (int j = 0; j < 4; ++j)
    t[ty0 + j][tx] = W[(size_t)(kt + ty0 + j) * N + nt + tx];
  __syncthreads();
#pragma unroll
  for (int j = 0; j < 4; ++j)
    Wt[(size_t)(nt + ty0 + j) * K + kt + tx] = (f16)t[tx][ty0 + j];
}

__global__ __launch_bounds__(256) void k_prep(
    const float* __restrict__ W1, f16* __restrict__ W1t,
    const float* __restrict__ W2, f16* __restrict__ W2t,
    const float* __restrict__ W3, f16* __restrict__ W3t,
    const float* __restrict__ W4, f16* __restrict__ W4t,
    const float* __restrict__ W5, f16* __restrict__ W5t,
    const float* __restrict__ emb, f16* __restrict__ logE) {
  __shared__ float t[32][33];
  const int b = blockIdx.x;
  if (b < 512) {
    transpose256(W1, W1t, 512, 1024, (b & 31) * 32, (b >> 5) * 32, t);
  } else if (b < 3584) {
    int b3 = b - 512;
    int z = b3 >> 10;
    int b4 = b3 & 1023;
    const float* W = z == 0 ? W2 : (z == 1 ? W3 : W4);
    f16* T = z == 0 ? W2t : (z == 1 ? W3t : W4t);
    transpose256(W, T, 1024, 1024, (b4 & 31) * 32, (b4 >> 5) * 32, t);
  } else if (b < 3840) {
    int b5 = b - 3584;
    transpose256(W5, W5t, 1024, 256, (b5 & 7) * 32, (b5 >> 3) * 32, t);
  } else {
    int i = (b - 3840) * 256 + threadIdx.x;
    logE[i] = (f16)logf(emb[i] * 256.0f);  // argmax-invariant *256 shift (full-precision log)
  }
}

// ============ shared pieces ============
__device__ __forceinline__ void stats_epilogue(char* lds, f32x4 (&acc)[8][4],
                                               f32x2* __restrict__ outPart,
                                               int bm0) {
  const int tid = threadIdx.x;
  const int lane = tid & 63;
  const int wid = tid >> 6;
  const int wm = wid >> 2, wn = wid & 3;
  const int r0 = (lane >> 4) * 4;
  const int cc = lane & 15;
  __builtin_amdgcn_s_barrier();
  float* stp = (float*)lds;
  float* stq = (float*)(lds + 4096);
#pragma unroll
  for (int mi = 0; mi < 8; ++mi) {
#pragma unroll
    for (int j = 0; j < 4; ++j) {
      float s = 0.f, q = 0.f;
#pragma unroll
      for (int ni = 0; ni < 4; ++ni) {
        float v = acc[mi][ni][j];
        s += v; q += v * v;
      }
#pragma unroll
      for (int d = 1; d < 16; d <<= 1) { s += __shfl_xor(s, d); q += __shfl_xor(q, d); }
      if (cc == 0) {
        int rl = wm * 128 + mi * 16 + r0 + j;
        stp[rl * 4 + wn] = s;
        stq[rl * 4 + wn] = q;
      }
    }
  }
  __syncthreads();
  if (tid < 256) {
    float s = stp[tid * 4] + stp[tid * 4 + 1] + stp[tid * 4 + 2] + stp[tid * 4 + 3];
    float q = stq[tid * 4] + stq[tid * 4 + 1] + stq[tid * 4 + 2] + stq[tid * 4 + 3];
    f32x2 pr; pr[0] = s; pr[1] = q;
    outPart[(size_t)(bm0 + tid) * 4 + blockIdx.y] = pr;
  }
}

// ============ shared 256x256 GEMM core (plain A), 2-barrier/K-tile ============
__device__ __forceinline__ void gemm256_core(
    const f16* __restrict__ A, const f16* __restrict__ Bt,
    char* lds, int bm0, int bn0, int K, f32x4 (&acc)[8][4]) {
  const int tid = threadIdx.x;
  const int lane = tid & 63;
  const int wid = tid >> 6;
  const int wm = wid >> 2;
  const int wn = wid & 3;
  const int NT = K >> 6;

  const int slin = tid * 16;
  const int lrow = slin >> 7;
  const int scol = (slin & 127) ^ ((lrow & 7) << 4);
  const char* Ab = (const char*)A;
  const char* Bb = (const char*)Bt;
  const uint32_t rs = (uint32_t)K * 2;

  const int klo = (lane >> 4) * 16;
  const int sw = (lane & 7) << 4;
  const uint32_t kx0 = (uint32_t)(klo ^ sw);
  const uint32_t kx1 = (uint32_t)((64 + klo) ^ sw);
  const uint32_t abase = (uint32_t)(wm * 128 + (lane & 15)) * 128;
  const uint32_t bbase = (uint32_t)(wn * 64 + (lane & 15)) * 128;

#pragma unroll
  for (int i = 0; i < 8; ++i)
#pragma unroll
    for (int j = 0; j < 4; ++j) acc[i][j] = 0.0f;

#define LDSA(buf) (lds + (buf)*32768)
#define LDSB(buf) (lds + 65536 + (buf)*32768)
#define STAGE_A(t, h)                                                              \
  {                                                                                \
    const char* src = Ab + (size_t)(bm0 + (h)*128 + lrow) * rs + ((t) << 7) + scol;\
    char* dst = LDSA((t)&1) + (h)*16384 + slin;                                    \
    gload_lds16(src, dst);                                                         \
    gload_lds16(src + (size_t)64 * rs, dst + 8192);                                \
  }
#define STAGE_B(t, h)                                                              \
  {                                                                                \
    const char* src = Bb + (size_t)(bn0 + (h)*128 + lrow) * rs + ((t) << 7) + scol;\
    char* dst = LDSB((t)&1) + (h)*16384 + slin;                                    \
    gload_lds16(src, dst);                                                         \
    gload_lds16(src + (size_t)64 * rs, dst + 8192);                                \
  }
#define HALF1(Acur, Bcur)                                                          \
  _Pragma("unroll") for (int ni = 0; ni < 4; ++ni) {                               \
    bF[ni][0] = *(const f16x8*)((Bcur) + bbase + ni * 2048 + kx0);                 \
    bF[ni][1] = *(const f16x8*)((Bcur) + bbase + ni * 2048 + kx1);                 \
  }                                                                                \
  {                                                                                \
    f16x8 aF[4][2];                                                                \
    _Pragma("unroll") for (int mi = 0; mi < 4; ++mi) {                             \
      aF[mi][0] = *(const f16x8*)((Acur) + abase + mi * 2048 + kx0);               \
      aF[mi][1] = *(const f16x8*)((Acur) + abase + mi * 2048 + kx1);               \
    }                                                                              \
    __builtin_amdgcn_s_setprio(1);                                                 \
    _Pragma("unroll") for (int mi = 0; mi < 4; ++mi)                               \
        _Pragma("unroll") for (int ni = 0; ni < 4; ++ni) {                         \
          acc[mi][ni] = mfma16(aF[mi][0], bF[ni][0], acc[mi][ni]);                 \
          acc[mi][ni] = mfma16(aF[mi][1], bF[ni][1], acc[mi][ni]);                 \
        }                                                                          \
    __builtin_amdgcn_s_setprio(0);                                                 \
  }
#define HALF2(Acur)                                                                \
  {                                                                                \
    f16x8 aF[4][2];                                                                \
    _Pragma("unroll") for (int mi = 0; mi < 4; ++mi) {                             \
      aF[mi][0] = *(const f16x8*)((Acur) + abase + (mi + 4) * 2048 + kx0);         \
      aF[mi][1] = *(const f16x8*)((Acur) + abase + (mi + 4) * 2048 + kx1);         \
    }                                                                              \
    __builtin_amdgcn_s_setprio(1);                                                 \
    _Pragma("unroll") for (int mi = 0; mi < 4; ++mi)                               \
        _Pragma("unroll") for (int ni = 0; ni < 4; ++ni) {                         \
          acc[mi + 4][ni] = mfma16(aF[mi][0], bF[ni][0], acc[mi + 4][ni]);         \
          acc[mi + 4][ni] = mfma16(aF[mi][1], bF[ni][1], acc[mi + 4][ni]);         \
        }                                                                          \
    __builtin_amdgcn_s_setprio(0);                                                 \
  }

  STAGE_A(0, 0); STAGE_A(0, 1); STAGE_B(0, 0); STAGE_B(0, 1);
  STAGE_B(1, 0); STAGE_B(1, 1);
  asm volatile("s_waitcnt vmcnt(4)");
  __builtin_amdgcn_s_barrier();
  __builtin_amdgcn_sched_barrier(0);

  f16x8 bF[4][2];
  for (int t = 0; t < NT - 2; ++t) {
    const char* Acur = LDSA(t & 1);
    const char* Bcur = LDSB(t & 1);
    STAGE_A(t + 1, 0); STAGE_A(t + 1, 1);
    HALF1(Acur, Bcur)
    __builtin_amdgcn_s_barrier();
    __builtin_amdgcn_sched_barrier(0);
    STAGE_B(t + 2, 0); STAGE_B(t + 2, 1);
    HALF2(Acur)
    asm volatile("s_waitcnt vmcnt(4)");
    __builtin_amdgcn_s_barrier();
    __builtin_amdgcn_sched_barrier(0);
  }
  {
    const char* Acur = LDSA((NT - 2) & 1);
    const char* Bcur = LDSB((NT - 2) & 1);
    STAGE_A(NT - 1, 0); STAGE_A(NT - 1, 1);
    HALF1(Acur, Bcur)
    __builtin_amdgcn_s_barrier();
    __builtin_amdgcn_sched_barrier(0);
    HALF2(Acur)
    asm volatile("s_waitcnt vmcnt(0)");
    __builtin_amdgcn_s_barrier();
    __builtin_amdgcn_sched_barrier(0);
  }
  {
    const char* Acur = LDSA((NT - 1) & 1);
    const char* Bcur = LDSB((NT - 1) & 1);
    HALF1(Acur, Bcur)
    HALF2(Acur)
  }
#undef STAGE_A
#undef HALF1
#undef HALF2
#undef LDSA
#undef LDSB
#undef STAGE_B
}

// ---- div-GEMM: per-row argmax partials over 64-col chunks ----
__global__ __launch_bounds__(512, 2) void k_gemm256_div(
    const f16* __restrict__ A, const f16* __restrict__ Bt,
    float* __restrict__ part_val, int* __restrict__ part_idx, int N, int K) {
  __shared__ char lds[131072];
  const int bm0 = blockIdx.x * 256;
  const int bn0 = blockIdx.y * 256;
  f32x4 acc[8][4];
  gemm256_core(A, Bt, lds, bm0, bn0, K, acc);

  const int lane = threadIdx.x & 63;
  const int wid = threadIdx.x >> 6;
  const int wm = wid >> 2, wn = wid & 3;
  const int r0 = (lane >> 4) * 4;
  const int cc = lane & 15;
  const int nch = N >> 6;
  const int chunk = (bn0 >> 6) + wn;
#pragma unroll
  for (int mi = 0; mi < 8; ++mi) {
#pragma unroll
    for (int j = 0; j < 4; ++j) {
      float v = acc[mi][0][j];
      int c = cc;
#pragma unroll
      for (int ni = 1; ni < 4; ++ni) {
        float v2 = acc[mi][ni][j];
        int c2 = ni * 16 + cc;
        if (v2 > v) { v = v2; c = c2; }
      }
#pragma unroll
      for (int d = 1; d < 16; d <<= 1) {
        float ov = __shfl_xor(v, d);
        int oc = __shfl_xor(c, d);
        if (ov > v || (ov == v && oc < c)) { v = ov; c = oc; }
      }
      if (cc == 0) {
        int r = bm0 + wm * 128 + mi * 16 + r0 + j;
        part_val[r * nch + chunk] = v;
        part_idx[r * nch + chunk] = bn0 + wn * 64 + c;
      }
    }
  }
}

// ---- L1: A = x (f32), fused cvt in A-stage; stats epilogue; h store ----
__global__ __launch_bounds__(512, 2) void k_gemm256_cvt(
    const float* __restrict__ A, const f16* __restrict__ Bt,
    f16* __restrict__ O, f32x2* __restrict__ outPart, int N, int K) {
  __shared__ char lds[131072];
  const int tid = threadIdx.x;
  const int lane = tid & 63;
  const int wid = tid >> 6;
  const int wm = wid >> 2;
  const int wn = wid & 3;
  const int bm0 = blockIdx.x * 256;
  const int bn0 = blockIdx.y * 256;
  const int NT = K >> 6;

  const int slin = tid * 16;
  const int lrow = slin >> 7;
  const int scol = (slin & 127) ^ ((lrow & 7) << 4);
  const char* Ab = (const char*)A;        // f32, row stride K*4
  const char* Bb = (const char*)Bt;
  const uint32_t rsA = (uint32_t)K * 4;
  const uint32_t rs = (uint32_t)K * 2;

  const int klo = (lane >> 4) * 16;
  const int sw = (lane & 7) << 4;
  const uint32_t kx0 = (uint32_t)(klo ^ sw);
  const uint32_t kx1 = (uint32_t)((64 + klo) ^ sw);
  const uint32_t abase = (uint32_t)(wm * 128 + (lane & 15)) * 128;
  const uint32_t bbase = (uint32_t)(wn * 64 + (lane & 15)) * 128;

  const int alrow = tid >> 3;
  const uint32_t acolbF = (uint32_t)(tid & 7) * 32;
  const uint32_t awcol = ((uint32_t)(tid & 7) * 16) ^ (uint32_t)((alrow & 7) << 4);
  f32x4 arf[4][2];

  f32x4 acc[8][4];
#pragma unroll
  for (int i = 0; i < 8; ++i)
#pragma unroll
    for (int j = 0; j < 4; ++j) acc[i][j] = 0.0f;

#define LDSA(buf) (lds + (buf)*32768)
#define LDSB(buf) (lds + 65536 + (buf)*32768)
#define STAGE_B(t, h)                                                              \
  {                                                                                \
    const char* src = Bb + (size_t)(bn0 + (h)*128 + lrow) * rs + ((t) << 7) + scol;\
    char* dst = LDSB((t)&1) + (h)*16384 + slin;                                    \
    gload_lds16(src, dst);                                                         \
    gload_lds16(src + (size_t)64 * rs, dst + 8192);                                \
  }
#define A_ISSUE(t1)                                                               \
  {                                                                               \
    const char* base_ = Ab + (size_t)(bm0 + alrow) * rsA + ((size_t)(t1) << 8) + acolbF; \
    _Pragma("unroll") for (int i = 0; i < 4; ++i) {                               \
      arf[i][0] = *(const f32x4*)(base_ + (size_t)(i * 64) * rsA);                \
      arf[i][1] = *(const f32x4*)(base_ + (size_t)(i * 64) * rsA + 16);           \
    }                                                                             \
  }
#define A_WRITE(t1)                                                               \
  {                                                                               \
    char* wb_ = LDSA((t1)&1);                                                     \
    _Pragma("unroll") for (int i = 0; i < 4; ++i) {                               \
      f16x8 o;                                                                    \
      _Pragma("unroll") for (int e = 0; e < 4; ++e) {                             \
        o[e] = (f16)arf[i][0][e];                                                 \
        o[e + 4] = (f16)arf[i][1][e];                                             \
      }                                                                           \
      *(f16x8*)(wb_ + (i >> 1) * 16384 + (alrow + (i & 1) * 64) * 128 + awcol) = o; \
    }                                                                             \
  }
#define HALF1(Acur, Bcur)                                                          \
  _Pragma("unroll") for (int ni = 0; ni < 4; ++ni) {                               \
    bF[ni][0] = *(const f16x8*)((Bcur) + bbase + ni * 2048 + kx0);                 \
    bF[ni][1] = *(const f16x8*)((Bcur) + bbase + ni * 2048 + kx1);                 \
  }                                                                                \
  {                                                                                \
    f16x8 aF[4][2];                                                                \
    _Pragma("unroll") for (int mi = 0; mi < 4; ++mi) {                             \
      aF[mi][0] = *(const f16x8*)((Acur) + abase + mi * 2048 + kx0);               \
      aF[mi][1] = *(const f16x8*)((Acur) + abase + mi * 2048 + kx1);               \
    }                                                                              \
    __builtin_amdgcn_s_setprio(1);                                                 \
    _Pragma("unroll") for (int mi = 0; mi < 4; ++mi)                               \
        _Pragma("unroll") for (int ni = 0; ni < 4; ++ni) {                         \
          acc[mi][ni] = mfma16(aF[mi][0], bF[ni][0], acc[mi][ni]);                 \
          acc[mi][ni] = mfma16(aF[mi][1], bF[ni][1], acc[mi][ni]);                 \
        }                                                                          \
    __builtin_amdgcn_s_setprio(0);                                                 \
  }
#define HALF2(Acur)                                                                \
  {                                                                                \
    f16x8 aF[4][2];                                                                \
    _Pragma("unroll") for (int mi = 0; mi < 4; ++mi) {                             \
      aF[mi][0] = *(const f16x8*)((Acur) + abase + (mi + 4) * 2048 + kx0);         \
      aF[mi][1] = *(const f16x8*)((Acur) + abase + (mi + 4) * 2048 + kx1);         \
    }                                                                              \
    __builtin_amdgcn_s_setprio(1);                                                 \
    _Pragma("unroll") for (int mi = 0; mi < 4; ++mi)                               \
        _Pragma("unroll") for (int ni = 0; ni < 4; ++ni) {                         \
          acc[mi + 4][ni] = mfma16(aF[mi][0], bF[ni][0], acc[mi + 4][ni]);         \
          acc[mi + 4][ni] = mfma16(aF[mi][1], bF[ni][1], acc[mi + 4][ni]);         \
        }                                                                          \
    __builtin_amdgcn_s_setprio(0);                                                 \
  }

  A_ISSUE(0)
  STAGE_B(0, 0); STAGE_B(0, 1); STAGE_B(1, 0); STAGE_B(1, 1);
  asm volatile("s_waitcnt vmcnt(8)");
  A_WRITE(0)
  asm volatile("s_waitcnt vmcnt(4) lgkmcnt(0)");
  __builtin_amdgcn_s_barrier();
  __builtin_amdgcn_sched_barrier(0);

  f16x8 bF[4][2];
  for (int t = 0; t < NT - 2; ++t) {
    const char* Acur = LDSA(t & 1);
    const char* Bcur = LDSB(t & 1);
    A_ISSUE(t + 1)
    HALF1(Acur, Bcur)
    __builtin_amdgcn_s_barrier();
    __builtin_amdgcn_sched_barrier(0);
    STAGE_B(t + 2, 0); STAGE_B(t + 2, 1);
    HALF2(Acur)
    asm volatile("s_waitcnt vmcnt(4)");
    A_WRITE(t + 1)
    asm volatile("s_waitcnt lgkmcnt(0)");
    __builtin_amdgcn_s_barrier();
    __builtin_amdgcn_sched_barrier(0);
  }
  {
    const char* Acur = LDSA((NT - 2) & 1);
    const char* Bcur = LDSB((NT - 2) & 1);
    A_ISSUE(NT - 1)
    HALF1(Acur, Bcur)
    __builtin_amdgcn_s_barrier();
    __builtin_amdgcn_sched_barrier(0);
    HALF2(Acur)
    asm volatile("s_waitcnt vmcnt(0)");
    A_WRITE(NT - 1)
    asm volatile("s_waitcnt lgkmcnt(0)");
    __builtin_amdgcn_s_barrier();
    __builtin_amdgcn_sched_barrier(0);
  }
  {
    const char* Acur = LDSA((NT - 1) & 1);
    const char* Bcur = LDSB((NT - 1) & 1);
    HALF1(Acur, Bcur)
    HALF2(Acur)
  }
#undef STAGE_B
#undef A_ISSUE
#undef A_WRITE
#undef HALF1
#undef HALF2
#undef LDSA
#undef LDSB

  stats_epilogue(lds, acc, outPart, bm0);

  const int r0 = (lane >> 4) * 4;
  const int cc = lane & 15;
#pragma unroll
  for (int mi = 0; mi < 8; ++mi) {
#pragma unroll
    for (int ni = 0; ni < 4; ++ni) {
      int r = bm0 + wm * 128 + mi * 16 + r0;
      int c = bn0 + wn * 64 + ni * 16 + cc;
#pragma unroll
      for (int j = 0; j < 4; ++j)
        O[(size_t)(r + j) * N + c] = (f16)acc[mi][ni][j];
    }
  }
}

// ======== consumer-LN fused GEMM + stats (L2/L3/L4), packed-f16 transform ========
__global__ __launch_bounds__(512, 2) void k_gemm256_ln(
    const f16* __restrict__ A, const f16* __restrict__ Bt,
    f16* __restrict__ O, const float* __restrict__ gw,
    const float* __restrict__ bw, const f32x2* __restrict__ inPart,
    f32x2* __restrict__ outPart, int N, int K) {
  __shared__ char lds[135168];  // A dbuf 2x32K @0, B dbuf 2x32K @65536, g/b 4K @131072
  const int GB = 131072;
  const int tid = threadIdx.x;
  const int lane = tid & 63;
  const int wid = tid >> 6;
  const int wm = wid >> 2;
  const int wn = wid & 3;
  const int bm0 = blockIdx.x * 256;
  const int bn0 = blockIdx.y * 256;
  const int NT = K >> 6;

  const int slin = tid * 16;
  const int lrow = slin >> 7;
  const int scol = (slin & 127) ^ ((lrow & 7) << 4);
  const char* Ab = (const char*)A;
  const char* Bb = (const char*)Bt;
  const uint32_t rs = (uint32_t)K * 2;

  const int klo = (lane >> 4) * 16;
  const int sw = (lane & 7) << 4;
  const uint32_t kx0 = (uint32_t)(klo ^ sw);
  const uint32_t kx1 = (uint32_t)((64 + klo) ^ sw);
  const uint32_t abase = (uint32_t)(wm * 128 + (lane & 15)) * 128;
  const uint32_t bbase = (uint32_t)(wn * 64 + (lane & 15)) * 128;

  const int alrow = tid >> 3;
  const uint32_t acolb = (uint32_t)(tid & 7) * 16;
  const uint32_t awcol = acolb ^ (uint32_t)((alrow & 7) << 4);
  f16 aSh[4], cSh[4];
  f16x8 ar[4];

  f32x4 acc[8][4];
#pragma unroll
  for (int i = 0; i < 8; ++i)
#pragma unroll
    for (int j = 0; j < 4; ++j) acc[i][j] = 0.0f;

#define LDSA(buf) (lds + (buf)*32768)
#define LDSB(buf) (lds + 65536 + (buf)*32768)
#define STAGE_B(t, h)                                                              \
  {                                                                                \
    const char* src = Bb + (size_t)(bn0 + (h)*128 + lrow) * rs + ((t) << 7) + scol;\
    char* dst = LDSB((t)&1) + (h)*16384 + slin;                                    \
    gload_lds16(src, dst);                                                         \
    gload_lds16(src + (size_t)64 * rs, dst + 8192);                                \
  }
#define A_ISSUE(t1)                                                               \
  {                                                                               \
    const char* base_ = Ab + (size_t)(bm0 + alrow) * rs + ((size_t)(t1) << 7) + acolb; \
    ar[0] = *(const f16x8*)(base_);                                               \
    ar[1] = *(const f16x8*)(base_ + (size_t)64 * rs);                             \
    ar[2] = *(const f16x8*)(base_ + (size_t)128 * rs);                            \
    ar[3] = *(const f16x8*)(base_ + (size_t)192 * rs);                            \
  }
// packed transform via ext-vector math: a' = relu((a*rstd + (-mu*rstd))*g + b)
#define A_WRITE(t1)                                                               \
  {                                                                               \
    uint32_t off_ = GB + (uint32_t)(t1)*128 + (uint32_t)(tid & 7) * 16;           \
    f16x8 gr = *(const f16x8*)(lds + off_);                                       \
    f16x8 br = *(const f16x8*)(lds + off_ + 2048);                                \
    char* wb_ = LDSA((t1)&1);                                                     \
    _Pragma("unroll") for (int i = 0; i < 4; ++i) {                               \
      f16x8 aS8, cS8, zz;                                                         \
      _Pragma("unroll") for (int p = 0; p < 8; ++p) {                             \
        aS8[p] = aSh[i]; cS8[p] = cSh[i]; zz[p] = (f16)0.f;                       \
      }                                                                           \
      f16x8 tt = ar[i] * aS8 + cS8;                                               \
      tt = tt * gr + br;                                                          \
      tt = __builtin_elementwise_max(tt, zz);                                     \
      *(f16x8*)(wb_ + (i >> 1) * 16384 + (alrow + (i & 1) * 64) * 128 + awcol) = tt; \
    }                                                                             \
  }

  // prologue: g/b -> LDS as f16; stats from partials; A(0) regs + B(0),B(1)
  if (tid < 256) {
    f32x4 g4 = ((const f32x4*)gw)[tid];
    f32x4 b4 = ((const f32x4*)bw)[tid];
    f16x4 gh, bh;
#pragma unroll
    for (int e = 0; e < 4; ++e) { gh[e] = (f16)g4[e]; bh[e] = (f16)b4[e]; }
    ((f16x4*)(lds + GB))[tid] = gh;
    ((f16x4*)(lds + GB + 2048))[tid] = bh;
  }
#pragma unroll
  for (int i = 0; i < 4; ++i) {
    int r = bm0 + (i >> 1) * 128 + (i & 1) * 64 + alrow;
    const f32x4* pp = (const f32x4*)(inPart + (size_t)r * 4);
    f32x4 p0 = pp[0], p1 = pp[1];
    float s = p0[0] + p0[2] + p1[0] + p1[2];
    float q = p0[1] + p0[3] + p1[1] + p1[3];
    float mu = s * (1.0f / 1024.0f);
    float var = q * (1.0f / 1024.0f) - mu * mu;
    float rstd = rsqrtf(var + LN_EPS);
    aSh[i] = (f16)rstd;
    cSh[i] = (f16)(-mu * rstd);
  }
  __builtin_amdgcn_sched_barrier(0);
  A_ISSUE(0)
  STAGE_B(0, 0); STAGE_B(0, 1); STAGE_B(1, 0); STAGE_B(1, 1);
  __builtin_amdgcn_sched_barrier(0);
  asm volatile("s_waitcnt lgkmcnt(0)");
  __builtin_amdgcn_s_barrier();               // g/b visible to all waves
  asm volatile("s_waitcnt vmcnt(8)");          // ar(0) landed
  A_WRITE(0)
  asm volatile("s_waitcnt vmcnt(4) lgkmcnt(0)");  // B(0) landed, A(0) written
  __builtin_amdgcn_s_barrier();
  __builtin_amdgcn_sched_barrier(0);

  for (int t = 0; t < NT; ++t) {
    const char* Acur = LDSA(t & 1);
    const char* Bcur = LDSB(t & 1);

    if (t + 1 < NT) { A_ISSUE(t + 1) }
    f16x8 bF[4][2];
#pragma unroll
    for (int ni = 0; ni < 4; ++ni) {
      bF[ni][0] = *(const f16x8*)(Bcur + bbase + ni * 2048 + kx0);
      bF[ni][1] = *(const f16x8*)(Bcur + bbase + ni * 2048 + kx1);
    }
    {
      f16x8 aF[4][2];
#pragma unroll
      for (int mi = 0; mi < 4; ++mi) {
        aF[mi][0] = *(const f16x8*)(Acur + abase + mi * 2048 + kx0);
        aF[mi][1] = *(const f16x8*)(Acur + abase + mi * 2048 + kx1);
      }
      __builtin_amdgcn_s_setprio(1);
#pragma unroll
      for (int mi = 0; mi < 4; ++mi)
#pragma unroll
        for (int ni = 0; ni < 4; ++ni) {
          acc[mi][ni] = mfma16(aF[mi][0], bF[ni][0], acc[mi][ni]);
          acc[mi][ni] = mfma16(aF[mi][1], bF[ni][1], acc[mi][ni]);
        }
      __builtin_amdgcn_s_setprio(0);
    }
    __builtin_amdgcn_s_barrier();
    __builtin_amdgcn_sched_barrier(0);

    if (t + 2 < NT) { STAGE_B(t + 2, 0); STAGE_B(t + 2, 1); }
    {
      f16x8 aF[4][2];
#pragma unroll
      for (int mi = 0; mi < 4; ++mi) {
        aF[mi][0] = *(const f16x8*)(Acur + abase + (mi + 4) * 2048 + kx0);
        aF[mi][1] = *(const f16x8*)(Acur + abase + (mi + 4) * 2048 + kx1);
      }
      __builtin_amdgcn_s_setprio(1);
#pragma unroll
      for (int mi = 0; mi < 4; ++mi)
#pragma unroll
        for (int ni = 0; ni < 4; ++ni) {
          acc[mi + 4][ni] = mfma16(aF[mi][0], bF[ni][0], acc[mi + 4][ni]);
          acc[mi + 4][ni] = mfma16(aF[mi][1], bF[ni][1], acc[mi + 4][ni]);
        }
      __builtin_amdgcn_s_setprio(0);
    }
    if (t + 1 < NT) {
      if (t + 2 < NT) { asm volatile("s_waitcnt vmcnt(4)"); }
      else            { asm volatile("s_waitcnt vmcnt(0)"); }
      A_WRITE(t + 1)
      asm volatile("s_waitcnt lgkmcnt(0)");
      __builtin_amdgcn_s_barrier();
      __builtin_amdgcn_sched_barrier(0);
    }
  }
#undef STAGE_B
#undef A_ISSUE
#undef A_WRITE
#undef LDSA
#undef LDSB

  stats_epilogue(lds, acc, outPart, bm0);

  const int r0 = (lane >> 4) * 4;
  const int cc = lane & 15;
#pragma unroll
  for (int mi = 0; mi < 8; ++mi) {
#pragma unroll
    for (int ni = 0; ni < 4; ++ni) {
      int r = bm0 + wm * 128 + mi * 16 + r0;
      int c = bn0 + wn * 64 + ni * 16 + cc;
#pragma unroll
      for (int j = 0; j < 4; ++j)
        O[(size_t)(r + j) * N + c] = (f16)acc[mi][ni][j];
    }
  }
}

// ======== fused LN(h4) -> G5 -> softmax, pipelined B dbuf, packed-f16 ========
__global__ __launch_bounds__(256) void k_gemm_sm(
    const f16* __restrict__ A, const f16* __restrict__ Bt,
    const float* __restrict__ gw, const float* __restrict__ bw,
    const f32x2* __restrict__ inPart, const float* __restrict__ bias,
    float* __restrict__ z, f16* __restrict__ ep, float* __restrict__ sm) {
  const int K = 1024;
  __shared__ char lds[77824];  // A 8K @0, B dbuf 2x32K @8192, g/b 4K @73728
  const int GBS = 73728;
  char* ldsA = lds;
  const int tid = threadIdx.x;
  const int lane = tid & 63;
  const int wn = tid >> 6;
  const int bm0 = blockIdx.x * 64;
  const char* Ab = (const char*)A;
  const char* Bb = (const char*)Bt;
  const uint32_t rs = (uint32_t)K * 2;
  const int cc = lane & 15;

  {
    f32x4 g4 = ((const f32x4*)gw)[tid];
    f32x4 b4 = ((const f32x4*)bw)[tid];
    f16x4 gh, bh;
#pragma unroll
    for (int e = 0; e < 4; ++e) { gh[e] = (f16)g4[e]; bh[e] = (f16)b4[e]; }
    ((f16x4*)(lds + GBS))[tid] = gh;
    ((f16x4*)(lds + GBS + 2048))[tid] = bh;
  }

  const int ar0 = tid >> 3;
  f16 aSh[2], cSh[2];
#pragma unroll
  for (int i = 0; i < 2; ++i) {
    int r = bm0 + ar0 + i * 32;
    const f32x4* pp = (const f32x4*)(inPart + (size_t)r * 4);
    f32x4 p0 = pp[0], p1 = pp[1];
    float s = p0[0] + p0[2] + p1[0] + p1[2];
    float q = p0[1] + p0[3] + p1[1] + p1[3];
    float mu = s * (1.0f / 1024.0f);
    float var = q * (1.0f / 1024.0f) - mu * mu;
    float rstd = rsqrtf(var + LN_EPS);
    aSh[i] = (f16)rstd;
    cSh[i] = (f16)(-mu * rstd);
  }
  const uint32_t acolb = (uint32_t)(tid & 7) * 16;
  const uint32_t awcol = acolb ^ (uint32_t)((ar0 & 7) << 4);

  uint32_t ra[2][4], rb[2][4];
  {
    const int sww = (lane & 7) << 4;
    const int gk = lane & 48;
#pragma unroll
    for (int kk = 0; kk < 2; ++kk) {
#pragma unroll
      for (int i = 0; i < 4; ++i) {
        uint32_t kb = (uint32_t)((kk * 64 + gk) ^ sww);
        ra[kk][i] = (uint32_t)(i * 16 + cc) * 128 + kb;
        rb[kk][i] = (uint32_t)(wn * 64 + i * 16 + cc) * 128 + kb;
      }
    }
  }

  f32x4 acc[4][4];
#pragma unroll
  for (int i = 0; i < 4; ++i)
#pragma unroll
    for (int j = 0; j < 4; ++j) acc[i][j] = 0.0f;

#define STAGE_BS(t)                                                               \
  {                                                                               \
    char* bdst = lds + 8192 + ((t)&1) * 32768;                                    \
    _Pragma("unroll") for (int i = 0; i < 8; ++i) {                               \
      int lin = i * 4096 + tid * 16;                                              \
      int row = lin >> 7;                                                         \
      int col = (lin & 127) ^ ((row & 7) << 4);                                   \
      gload_lds16(Bb + (size_t)row * rs + ((size_t)(t) << 7) + col, bdst + lin);  \
    }                                                                             \
  }

  STAGE_BS(0)
  asm volatile("s_waitcnt lgkmcnt(0)");
  __builtin_amdgcn_s_barrier();   // g/b visible
  __builtin_amdgcn_sched_barrier(0);

  for (int t = 0; t < 16; ++t) {
    const char* abase_ = Ab + (size_t)(bm0 + ar0) * rs + ((size_t)t << 7) + acolb;
    f16x8 a0 = *(const f16x8*)abase_;
    f16x8 a1 = *(const f16x8*)(abase_ + (size_t)32 * rs);
    if (t + 1 < 16) { STAGE_BS(t + 1) }
    if (t + 1 < 16) { asm volatile("s_waitcnt vmcnt(8)"); }  // drains B(t)+a0,a1
    else            { asm volatile("s_waitcnt vmcnt(0)"); }
    {
      uint32_t off_ = GBS + (uint32_t)t * 128 + (uint32_t)(tid & 7) * 16;
      f16x8 gr = *(const f16x8*)(lds + off_);
      f16x8 br = *(const f16x8*)(lds + off_ + 2048);
      f16x8 aS0, cS0, aS1, cS1, zz;
#pragma unroll
      for (int p = 0; p < 8; ++p) {
        aS0[p] = aSh[0]; cS0[p] = cSh[0];
        aS1[p] = aSh[1]; cS1[p] = cSh[1];
        zz[p] = (f16)0.f;
      }
      f16x8 t0 = a0 * aS0 + cS0;
      f16x8 t1 = a1 * aS1 + cS1;
      t0 = t0 * gr + br;
      t1 = t1 * gr + br;
      t0 = __builtin_elementwise_max(t0, zz);
      t1 = __builtin_elementwise_max(t1, zz);
      *(f16x8*)(ldsA + ar0 * 128 + awcol) = t0;
      *(f16x8*)(ldsA + (ar0 + 32) * 128 + awcol) = t1;
    }
    asm volatile("s_waitcnt lgkmcnt(0)");
    __builtin_amdgcn_s_barrier();   // ldsA written by all; B(t) landed
    __builtin_amdgcn_sched_barrier(0);
    {
      const char* Bcur = lds + 8192 + (t & 1) * 32768;
#pragma unroll
      for (int kk = 0; kk < 2; ++kk) {
        f16x8 af[4], bfv[4];
#pragma unroll
        for (int i = 0; i < 4; ++i) af[i] = *(const f16x8*)(ldsA + ra[kk][i]);
#pragma unroll
        for (int i = 0; i < 4; ++i) bfv[i] = *(const f16x8*)(Bcur + rb[kk][i]);
#pragma unroll
        for (int mi = 0; mi < 4; ++mi)
#pragma unroll
          for (int ni = 0; ni < 4; ++ni)
            acc[mi][ni] = mfma16(af[mi], bfv[ni], acc[mi][ni]);
      }
    }
    __builtin_amdgcn_s_barrier();   // all reads of ldsA / B(t) done before overwrite
    __builtin_amdgcn_sched_barrier(0);
  }
#undef STAGE_BS

  // ---- softmax epilogue over full 256-wide rows (fast-exp; keep logf for sm) ----
  __syncthreads();
  float* stm = (float*)lds;
  float* sts = (float*)(lds + 1024);
  float* rowm = (float*)(lds + 2048);
  float* rows_ = (float*)(lds + 2304);

  const int r0 = (lane >> 4) * 4;
  float bvv[4];
#pragma unroll
  for (int ni = 0; ni < 4; ++ni) bvv[ni] = bias[wn * 64 + ni * 16 + cc];

#pragma unroll
  for (int mi = 0; mi < 4; ++mi) {
#pragma unroll
    for (int j = 0; j < 4; ++j) {
      float m = -3.4e38f;
#pragma unroll
      for (int ni = 0; ni < 4; ++ni) m = fmaxf(m, acc[mi][ni][j] + bvv[ni]);
#pragma unroll
      for (int d = 1; d < 16; d <<= 1) m = fmaxf(m, __shfl_xor(m, d));
      if (cc == 0) stm[wn * 64 + mi * 16 + r0 + j] = m;
    }
  }
  __syncthreads();
  if (tid < 64) {
    float m = fmaxf(fmaxf(stm[tid], stm[64 + tid]), fmaxf(stm[128 + tid], stm[192 + tid]));
    rowm[tid] = m;
  }
  __syncthreads();
#pragma unroll
  for (int mi = 0; mi < 4; ++mi) {
#pragma unroll
    for (int j = 0; j < 4; ++j) {
      int r = mi * 16 + r0 + j;
      float m = rowm[r];
      float s = 0.f;
#pragma unroll
      for (int ni = 0; ni < 4; ++ni) s += __expf(acc[mi][ni][j] + bvv[ni] - m);
#pragma unroll
      for (int d = 1; d < 16; d <<= 1) s += __shfl_xor(s, d);
      if (cc == 0) sts[wn * 64 + r] = s;
    }
  }
  __syncthreads();
  if (tid < 64) {
    float s = sts[tid] + sts[64 + tid] + sts[128 + tid] + sts[192 + tid];
    rows_[tid] = s;
    sm[bm0 + tid] = rowm[tid] + logf(s);   // full-precision log protects p = z - sm
  }
  __syncthreads();
#pragma unroll
  for (int mi = 0; mi < 4; ++mi) {
#pragma unroll
    for (int j = 0; j < 4; ++j) {
      int r = mi * 16 + r0 + j;
      float m = rowm[r];
      float inv = 1.0f / rows_[r];
      float* zp = z + (size_t)(bm0 + r) * 256;
      f16* epp = ep + (size_t)(bm0 + r) * 256;
#pragma unroll
      for (int ni = 0; ni < 4; ++ni) {
        int c = wn * 64 + ni * 16 + cc;
        float zz = acc[mi][ni][j] + bvv[ni];
        zp[c] = zz;
        epp[c] = (f16)(__expf(zz - m) * inv);
      }
    }
  }
}

// ---------------- finalize: argmax reduce, gather q, fp32 kl from z,sm ----------------
__global__ __launch_bounds__(256) void k_final(
    const float* __restrict__ part_val, const int* __restrict__ part_idx,
    const float* __restrict__ z, const float* __restrict__ sm,
    const float* __restrict__ emb, const float* __restrict__ masks,
    float* __restrict__ q, float* __restrict__ blockloss) {
  __shared__ float ls[4];
  int lane = threadIdx.x & 63;
  int w = threadIdx.x >> 6;
  int row = blockIdx.x * 4 + w;
  float v = -3.4e38f;
  int c = 0x7fffffff;
  if (lane < 16) { v = part_val[row * 16 + lane]; c = part_idx[row * 16 + lane]; }
#pragma unroll
  for (int d = 1; d < 16; d <<= 1) {
    float ov = __shfl_xor(v, d);
    int oc = __shfl_xor(c, d);
    if (ov > v || (ov == v && oc < c)) { v = ov; c = oc; }
  }
  int code = __shfl(c, 0);
  f32x4 ev = ((const f32x4*)(emb + (size_t)code * 256))[lane];
  ((f32x4*)(q + (size_t)row * 256))[lane] = ev;
  f32x4 zv = ((const f32x4*)(z + (size_t)row * 256))[lane];
  float smr = sm[row];
  float kl = 0.f;
#pragma unroll
  for (int j = 0; j < 4; ++j) {
    float pj = zv[j] - smr;
    kl += __expf(pj) * (pj - __logf(ev[j]));
  }
#pragma unroll
  for (int d = 1; d < 64; d <<= 1) kl += __shfl_xor(kl, d);
  if (lane == 0) ls[w] = kl * masks[row];
  __syncthreads();
  if (threadIdx.x == 0) blockloss[blockIdx.x] = ls[0] + ls[1] + ls[2] + ls[3];
}

__global__ __launch_bounds__(256) void k_loss_reduce(const float* __restrict__ bl,
                                                     float* __restrict__ out) {
  __shared__ float s[256];
  float a = 0.f;
#pragma unroll
  for (int i = 0; i < 16; ++i) a += bl[threadIdx.x + i * 256];
  s[threadIdx.x] = a;
  __syncthreads();
  for (int st = 128; st > 0; st >>= 1) {
    if (threadIdx.x < st) s[threadIdx.x] += s[threadIdx.x + st];
    __syncthreads();
  }
  if (threadIdx.x == 0) out[0] = s[0] * (0.25f / 16.0f);
}

// ---------------- launch ----------------
extern "C" void kernel_launch(void* const* d_in, const int* in_sizes, int n_in,
                              void* d_out, int out_size, void* d_ws, size_t ws_size,
                              hipStream_t stream) {
  const float* x = (const float*)d_in[0];
  const float* masks = (const float*)d_in[1];
  const float* W1 = (const float*)d_in[2];
  const float* g1 = (const float*)d_in[3];
  const float* b1 = (const float*)d_in[4];
  const float* W2 = (const float*)d_in[5];
  const float* g2 = (const float*)d_in[6];
  const float* b2 = (const float*)d_in[7];
  const float* W3 = (const float*)d_in[8];
  const float* g3 = (const float*)d_in[9];
  const float* b3 = (const float*)d_in[10];
  const float* W4 = (const float*)d_in[11];
  const float* g4 = (const float*)d_in[12];
  const float* b4 = (const float*)d_in[13];
  const float* W5 = (const float*)d_in[14];
  const float* b5 = (const float*)d_in[15];
  const float* emb = (const float*)d_in[16];

  const int M = 16384;  // B*T
  char* ws = (char*)d_ws;
  f16* bufA = (f16*)(ws);                       // 32 MB ping
  f16* bufB = (f16*)(ws + (32ull << 20));       // 32 MB pong
  f16* W1t = (f16*)(ws + (64ull << 20));        // 1 MB  [1024][512]
  f16* W2t = (f16*)(ws + (65ull << 20));        // 2 MB
  f16* W3t = (f16*)(ws + (67ull << 20));        // 2 MB
  f16* W4t = (f16*)(ws + (69ull << 20));        // 2 MB
  f16* W5t = (f16*)(ws + (71ull << 20));        // 0.5 MB [256][1024]
  f16* logE = (f16*)(ws + (72ull << 20));       // 0.5 MB [1024][256]
  float* part_val = (float*)(ws + (73ull << 20));     // 1 MB
  int* part_idx = (int*)(ws + (74ull << 20));         // 1 MB
  float* blockloss = (float*)(ws + (75ull << 20));    // 16 KB
  float* sm = (float*)(ws + (76ull << 20));           // 64 KB
  f32x2* partA = (f32x2*)(ws + (77ull << 20));        // 512 KB [16384][4]
  f32x2* partB = (f32x2*)(ws + (78ull << 20));        // 512 KB
  f16* ep = (f16*)(ws + (16ull << 20));               // 8 MB, aliases bufA upper half

  float* z = (float*)d_out;                 // [16384][256]
  float* q = z + (size_t)M * 256;           // [16384][256]
  float* lossp = z + 2ull * M * 256;        // [1]

  k_prep<<<4864, 256, 0, stream>>>(W1, W1t, W2, W2t, W3, W3t, W4, W4t,
                                   W5, W5t, emb, logE);
  k_gemm256_cvt<<<dim3(64, 4), 512, 0, stream>>>(x, W1t, bufA, partA, 1024, 512);
  k_gemm256_ln<<<dim3(64, 4), 512, 0, stream>>>(bufA, W2t, bufB, g1, b1, partA, partB, 1024, 1024);
  k_gemm256_ln<<<dim3(64, 4), 512, 0, stream>>>(bufB, W3t, bufA, g2, b2, partB, partA, 1024, 1024);
  k_gemm256_ln<<<dim3(64, 4), 512, 0, stream>>>(bufA, W4t, bufB, g3, b3, partA, partB, 1024, 1024);
  k_gemm_sm<<<256, 256, 0, stream>>>(bufB, W5t, g4, b4, partB, b5, z, ep, sm);
  k_gemm256_div<<<dim3(64, 4), 512, 0, stream>>>(ep, logE, part_val, part_idx, 1024, 256);
  k_final<<<4096, 256, 0, stream>>>(part_val, part_idx, z, sm, emb, masks, q, blockloss);
  k_loss_reduce<<<1, 256, 0, stream>>>(blockloss, lossp);
}

// Round 21
// 237.444 us; speedup vs baseline: 1.1252x; 1.0011x over previous
//
#include <hip/hip_runtime.h>
#include <hip/hip_fp16.h>
#include <stdint.h>

typedef __attribute__((ext_vector_type(4))) float f32x4;
typedef __attribute__((ext_vector_type(2))) float f32x2;
typedef _Float16 f16;
typedef __attribute__((ext_vector_type(8))) _Float16 f16x8;
typedef __attribute__((ext_vector_type(4))) _Float16 f16x4;

#define LN_EPS 1e-5f

// ---------------- helpers ----------------
__device__ __forceinline__ void gload_lds16(const void* g, void* l) {
  __builtin_amdgcn_global_load_lds(
      (__attribute__((address_space(1))) void*)(uintptr_t)g,
      (__attribute__((address_space(3))) void*)(uint32_t)(uintptr_t)l,
      16, 0, 0);
}

__device__ __forceinline__ f32x4 mfma16(f16x8 a, f16x8 b, f32x4 c) {
  return __builtin_amdgcn_mfma_f32_16x16x32_f16(a, b, c, 0, 0, 0);
}

// ---------------- prep megakernel (weights + logE) ----------------
__device__ __forceinline__ void transpose256(const float* __restrict__ W,
                                             f16* __restrict__ Wt, int K, int N,
                                             int nt, int kt, float (*t)[33]) {
  int tx = threadIdx.x & 31;
  int ty0 = (threadIdx.x >> 5) * 4;
#pragma unroll
  for (int j = 0; j < 4; ++j)
    t[ty0 + j][tx] = W[(size_t)(kt + ty0 + j) * N + nt + tx];
  __syncthreads();
#pragma unroll
  for (int j = 0; j < 4; ++j)
    Wt[(size_t)(nt + ty0 + j) * K + kt + tx] = (f16)t[tx][ty0 + j];
}

__global__ __launch_bounds__(256) void k_prep(
    const float* __restrict__ W1, f16* __restrict__ W1t,
    const float* __restrict__ W2, f16* __restrict__ W2t,
    const float* __restrict__ W3, f16* __restrict__ W3t,
    const float* __restrict__ W4, f16* __restrict__ W4t,
    const float* __restrict__ W5, f16* __restrict__ W5t,
    const float* __restrict__ emb, f16* __restrict__ logE) {
  __shared__ float t[32][33];
  const int b = blockIdx.x;
  if (b < 512) {
    transpose256(W1, W1t, 512, 1024, (b & 31) * 32, (b >> 5) * 32, t);
  } else if (b < 3584) {
    int b3 = b - 512;
    int z = b3 >> 10;
    int b4 = b3 & 1023;
    const float* W = z == 0 ? W2 : (z == 1 ? W3 : W4);
    f16* T = z == 0 ? W2t : (z == 1 ? W3t : W4t);
    transpose256(W, T, 1024, 1024, (b4 & 31) * 32, (b4 >> 5) * 32, t);
  } else if (b < 3840) {
    int b5 = b - 3584;
    transpose256(W5, W5t, 1024, 256, (b5 & 7) * 32, (b5 >> 3) * 32, t);
  } else {
    int i = (b - 3840) * 256 + threadIdx.x;
    // argmax-invariant *256 shift; __logf err 1e-6 << f16 rounding 5e-4
    logE[i] = (f16)__logf(emb[i] * 256.0f);
  }
}

// ============ shared pieces ============
__device__ __forceinline__ void stats_epilogue(char* lds, f32x4 (&acc)[8][4],
                                               f32x2* __restrict__ outPart,
                                               int bm0) {
  const int tid = threadIdx.x;
  const int lane = tid & 63;
  const int wid = tid >> 6;
  const int wm = wid >> 2, wn = wid & 3;
  const int r0 = (lane >> 4) * 4;
  const int cc = lane & 15;
  __builtin_amdgcn_s_barrier();
  float* stp = (float*)lds;
  float* stq = (float*)(lds + 4096);
#pragma unroll
  for (int mi = 0; mi < 8; ++mi) {
#pragma unroll
    for (int j = 0; j < 4; ++j) {
      float s = 0.f, q = 0.f;
#pragma unroll
      for (int ni = 0; ni < 4; ++ni) {
        float v = acc[mi][ni][j];
        s += v; q += v * v;
      }
#pragma unroll
      for (int d = 1; d < 16; d <<= 1) { s += __shfl_xor(s, d); q += __shfl_xor(q, d); }
      if (cc == 0) {
        int rl = wm * 128 + mi * 16 + r0 + j;
        stp[rl * 4 + wn] = s;
        stq[rl * 4 + wn] = q;
      }
    }
  }
  __syncthreads();
  if (tid < 256) {
    float s = stp[tid * 4] + stp[tid * 4 + 1] + stp[tid * 4 + 2] + stp[tid * 4 + 3];
    float q = stq[tid * 4] + stq[tid * 4 + 1] + stq[tid * 4 + 2] + stq[tid * 4 + 3];
    f32x2 pr; pr[0] = s; pr[1] = q;
    outPart[(size_t)(bm0 + tid) * 4 + blockIdx.y] = pr;
  }
}

// ============ shared 256x256 GEMM core (plain A), 2-barrier/K-tile ============
__device__ __forceinline__ void gemm256_core(
    const f16* __restrict__ A, const f16* __restrict__ Bt,
    char* lds, int bm0, int bn0, int K, f32x4 (&acc)[8][4]) {
  const int tid = threadIdx.x;
  const int lane = tid & 63;
  const int wid = tid >> 6;
  const int wm = wid >> 2;
  const int wn = wid & 3;
  const int NT = K >> 6;

  const int slin = tid * 16;
  const int lrow = slin >> 7;
  const int scol = (slin & 127) ^ ((lrow & 7) << 4);
  const char* Ab = (const char*)A;
  const char* Bb = (const char*)Bt;
  const uint32_t rs = (uint32_t)K * 2;

  const int klo = (lane >> 4) * 16;
  const int sw = (lane & 7) << 4;
  const uint32_t kx0 = (uint32_t)(klo ^ sw);
  const uint32_t kx1 = (uint32_t)((64 + klo) ^ sw);
  const uint32_t abase = (uint32_t)(wm * 128 + (lane & 15)) * 128;
  const uint32_t bbase = (uint32_t)(wn * 64 + (lane & 15)) * 128;

#pragma unroll
  for (int i = 0; i < 8; ++i)
#pragma unroll
    for (int j = 0; j < 4; ++j) acc[i][j] = 0.0f;

#define LDSA(buf) (lds + (buf)*32768)
#define LDSB(buf) (lds + 65536 + (buf)*32768)
#define STAGE_A(t, h)                                                              \
  {                                                                                \
    const char* src = Ab + (size_t)(bm0 + (h)*128 + lrow) * rs + ((t) << 7) + scol;\
    char* dst = LDSA((t)&1) + (h)*16384 + slin;                                    \
    gload_lds16(src, dst);                                                         \
    gload_lds16(src + (size_t)64 * rs, dst + 8192);                                \
  }
#define STAGE_B(t, h)                                                              \
  {                                                                                \
    const char* src = Bb + (size_t)(bn0 + (h)*128 + lrow) * rs + ((t) << 7) + scol;\
    char* dst = LDSB((t)&1) + (h)*16384 + slin;                                    \
    gload_lds16(src, dst);                                                         \
    gload_lds16(src + (size_t)64 * rs, dst + 8192);                                \
  }
#define HALF1(Acur, Bcur)                                                          \
  _Pragma("unroll") for (int ni = 0; ni < 4; ++ni) {                               \
    bF[ni][0] = *(const f16x8*)((Bcur) + bbase + ni * 2048 + kx0);                 \
    bF[ni][1] = *(const f16x8*)((Bcur) + bbase + ni * 2048 + kx1);                 \
  }                                                                                \
  {                                                                                \
    f16x8 aF[4][2];                                                                \
    _Pragma("unroll") for (int mi = 0; mi < 4; ++mi) {                             \
      aF[mi][0] = *(const f16x8*)((Acur) + abase + mi * 2048 + kx0);               \
      aF[mi][1] = *(const f16x8*)((Acur) + abase + mi * 2048 + kx1);               \
    }                                                                              \
    __builtin_amdgcn_s_setprio(1);                                                 \
    _Pragma("unroll") for (int mi = 0; mi < 4; ++mi)                               \
        _Pragma("unroll") for (int ni = 0; ni < 4; ++ni) {                         \
          acc[mi][ni] = mfma16(aF[mi][0], bF[ni][0], acc[mi][ni]);                 \
          acc[mi][ni] = mfma16(aF[mi][1], bF[ni][1], acc[mi][ni]);                 \
        }                                                                          \
    __builtin_amdgcn_s_setprio(0);                                                 \
  }
#define HALF2(Acur)                                                                \
  {                                                                                \
    f16x8 aF[4][2];                                                                \
    _Pragma("unroll") for (int mi = 0; mi < 4; ++mi) {                             \
      aF[mi][0] = *(const f16x8*)((Acur) + abase + (mi + 4) * 2048 + kx0);         \
      aF[mi][1] = *(const f16x8*)((Acur) + abase + (mi + 4) * 2048 + kx1);         \
    }                                                                              \
    __builtin_amdgcn_s_setprio(1);                                                 \
    _Pragma("unroll") for (int mi = 0; mi < 4; ++mi)                               \
        _Pragma("unroll") for (int ni = 0; ni < 4; ++ni) {                         \
          acc[mi + 4][ni] = mfma16(aF[mi][0], bF[ni][0], acc[mi + 4][ni]);         \
          acc[mi + 4][ni] = mfma16(aF[mi][1], bF[ni][1], acc[mi + 4][ni]);         \
        }                                                                          \
    __builtin_amdgcn_s_setprio(0);                                                 \
  }

  STAGE_A(0, 0); STAGE_A(0, 1); STAGE_B(0, 0); STAGE_B(0, 1);
  STAGE_B(1, 0); STAGE_B(1, 1);
  asm volatile("s_waitcnt vmcnt(4)");
  __builtin_amdgcn_s_barrier();
  __builtin_amdgcn_sched_barrier(0);

  f16x8 bF[4][2];
  for (int t = 0; t < NT - 2; ++t) {
    const char* Acur = LDSA(t & 1);
    const char* Bcur = LDSB(t & 1);
    STAGE_A(t + 1, 0); STAGE_A(t + 1, 1);
    HALF1(Acur, Bcur)
    __builtin_amdgcn_s_barrier();
    __builtin_amdgcn_sched_barrier(0);
    STAGE_B(t + 2, 0); STAGE_B(t + 2, 1);
    HALF2(Acur)
    asm volatile("s_waitcnt vmcnt(4)");
    __builtin_amdgcn_s_barrier();
    __builtin_amdgcn_sched_barrier(0);
  }
  {
    const char* Acur = LDSA((NT - 2) & 1);
    const char* Bcur = LDSB((NT - 2) & 1);
    STAGE_A(NT - 1, 0); STAGE_A(NT - 1, 1);
    HALF1(Acur, Bcur)
    __builtin_amdgcn_s_barrier();
    __builtin_amdgcn_sched_barrier(0);
    HALF2(Acur)
    asm volatile("s_waitcnt vmcnt(0)");
    __builtin_amdgcn_s_barrier();
    __builtin_amdgcn_sched_barrier(0);
  }
  {
    const char* Acur = LDSA((NT - 1) & 1);
    const char* Bcur = LDSB((NT - 1) & 1);
    HALF1(Acur, Bcur)
    HALF2(Acur)
  }
#undef STAGE_A
#undef HALF1
#undef HALF2
#undef LDSA
#undef LDSB
#undef STAGE_B
}

// ---- div-GEMM: per-row argmax partials over 64-col chunks ----
__global__ __launch_bounds__(512, 2) void k_gemm256_div(
    const f16* __restrict__ A, const f16* __restrict__ Bt,
    float* __restrict__ part_val, int* __restrict__ part_idx, int N, int K) {
  __shared__ char lds[131072];
  const int bm0 = blockIdx.x * 256;
  const int bn0 = blockIdx.y * 256;
  f32x4 acc[8][4];
  gemm256_core(A, Bt, lds, bm0, bn0, K, acc);

  const int lane = threadIdx.x & 63;
  const int wid = threadIdx.x >> 6;
  const int wm = wid >> 2, wn = wid & 3;
  const int r0 = (lane >> 4) * 4;
  const int cc = lane & 15;
  const int nch = N >> 6;
  const int chunk = (bn0 >> 6) + wn;
#pragma unroll
  for (int mi = 0; mi < 8; ++mi) {
#pragma unroll
    for (int j = 0; j < 4; ++j) {
      float v = acc[mi][0][j];
      int c = cc;
#pragma unroll
      for (int ni = 1; ni < 4; ++ni) {
        float v2 = acc[mi][ni][j];
        int c2 = ni * 16 + cc;
        if (v2 > v) { v = v2; c = c2; }
      }
#pragma unroll
      for (int d = 1; d < 16; d <<= 1) {
        float ov = __shfl_xor(v, d);
        int oc = __shfl_xor(c, d);
        if (ov > v || (ov == v && oc < c)) { v = ov; c = oc; }
      }
      if (cc == 0) {
        int r = bm0 + wm * 128 + mi * 16 + r0 + j;
        part_val[r * nch + chunk] = v;
        part_idx[r * nch + chunk] = bn0 + wn * 64 + c;
      }
    }
  }
}

// ---- L1: A = x (f32), fused cvt in A-stage; stats epilogue; h store ----
__global__ __launch_bounds__(512, 2) void k_gemm256_cvt(
    const float* __restrict__ A, const f16* __restrict__ Bt,
    f16* __restrict__ O, f32x2* __restrict__ outPart, int N, int K) {
  __shared__ char lds[131072];
  const int tid = threadIdx.x;
  const int lane = tid & 63;
  const int wid = tid >> 6;
  const int wm = wid >> 2;
  const int wn = wid & 3;
  const int bm0 = blockIdx.x * 256;
  const int bn0 = blockIdx.y * 256;
  const int NT = K >> 6;

  const int slin = tid * 16;
  const int lrow = slin >> 7;
  const int scol = (slin & 127) ^ ((lrow & 7) << 4);
  const char* Ab = (const char*)A;        // f32, row stride K*4
  const char* Bb = (const char*)Bt;
  const uint32_t rsA = (uint32_t)K * 4;
  const uint32_t rs = (uint32_t)K * 2;

  const int klo = (lane >> 4) * 16;
  const int sw = (lane & 7) << 4;
  const uint32_t kx0 = (uint32_t)(klo ^ sw);
  const uint32_t kx1 = (uint32_t)((64 + klo) ^ sw);
  const uint32_t abase = (uint32_t)(wm * 128 + (lane & 15)) * 128;
  const uint32_t bbase = (uint32_t)(wn * 64 + (lane & 15)) * 128;

  const int alrow = tid >> 3;
  const uint32_t acolbF = (uint32_t)(tid & 7) * 32;
  const uint32_t awcol = ((uint32_t)(tid & 7) * 16) ^ (uint32_t)((alrow & 7) << 4);
  f32x4 arf[4][2];

  f32x4 acc[8][4];
#pragma unroll
  for (int i = 0; i < 8; ++i)
#pragma unroll
    for (int j = 0; j < 4; ++j) acc[i][j] = 0.0f;

#define LDSA(buf) (lds + (buf)*32768)
#define LDSB(buf) (lds + 65536 + (buf)*32768)
#define STAGE_B(t, h)                                                              \
  {                                                                                \
    const char* src = Bb + (size_t)(bn0 + (h)*128 + lrow) * rs + ((t) << 7) + scol;\
    char* dst = LDSB((t)&1) + (h)*16384 + slin;                                    \
    gload_lds16(src, dst);                                                         \
    gload_lds16(src + (size_t)64 * rs, dst + 8192);                                \
  }
#define A_ISSUE(t1)                                                               \
  {                                                                               \
    const char* base_ = Ab + (size_t)(bm0 + alrow) * rsA + ((size_t)(t1) << 8) + acolbF; \
    _Pragma("unroll") for (int i = 0; i < 4; ++i) {                               \
      arf[i][0] = *(const f32x4*)(base_ + (size_t)(i * 64) * rsA);                \
      arf[i][1] = *(const f32x4*)(base_ + (size_t)(i * 64) * rsA + 16);           \
    }                                                                             \
  }
#define A_WRITE(t1)                                                               \
  {                                                                               \
    char* wb_ = LDSA((t1)&1);                                                     \
    _Pragma("unroll") for (int i = 0; i < 4; ++i) {                               \
      f16x8 o;                                                                    \
      _Pragma("unroll") for (int e = 0; e < 4; ++e) {                             \
        o[e] = (f16)arf[i][0][e];                                                 \
        o[e + 4] = (f16)arf[i][1][e];                                             \
      }                                                                           \
      *(f16x8*)(wb_ + (i >> 1) * 16384 + (alrow + (i & 1) * 64) * 128 + awcol) = o; \
    }                                                                             \
  }
#define HALF1(Acur, Bcur)                                                          \
  _Pragma("unroll") for (int ni = 0; ni < 4; ++ni) {                               \
    bF[ni][0] = *(const f16x8*)((Bcur) + bbase + ni * 2048 + kx0);                 \
    bF[ni][1] = *(const f16x8*)((Bcur) + bbase + ni * 2048 + kx1);                 \
  }                                                                                \
  {                                                                                \
    f16x8 aF[4][2];                                                                \
    _Pragma("unroll") for (int mi = 0; mi < 4; ++mi) {                             \
      aF[mi][0] = *(const f16x8*)((Acur) + abase + mi * 2048 + kx0);               \
      aF[mi][1] = *(const f16x8*)((Acur) + abase + mi * 2048 + kx1);               \
    }                                                                              \
    __builtin_amdgcn_s_setprio(1);                                                 \
    _Pragma("unroll") for (int mi = 0; mi < 4; ++mi)                               \
        _Pragma("unroll") for (int ni = 0; ni < 4; ++ni) {                         \
          acc[mi][ni] = mfma16(aF[mi][0], bF[ni][0], acc[mi][ni]);                 \
          acc[mi][ni] = mfma16(aF[mi][1], bF[ni][1], acc[mi][ni]);                 \
        }                                                                          \
    __builtin_amdgcn_s_setprio(0);                                                 \
  }
#define HALF2(Acur)                                                                \
  {                                                                                \
    f16x8 aF[4][2];                                                                \
    _Pragma("unroll") for (int mi = 0; mi < 4; ++mi) {                             \
      aF[mi][0] = *(const f16x8*)((Acur) + abase + (mi + 4) * 2048 + kx0);         \
      aF[mi][1] = *(const f16x8*)((Acur) + abase + (mi + 4) * 2048 + kx1);         \
    }                                                                              \
    __builtin_amdgcn_s_setprio(1);                                                 \
    _Pragma("unroll") for (int mi = 0; mi < 4; ++mi)                               \
        _Pragma("unroll") for (int ni = 0; ni < 4; ++ni) {                         \
          acc[mi + 4][ni] = mfma16(aF[mi][0], bF[ni][0], acc[mi + 4][ni]);         \
          acc[mi + 4][ni] = mfma16(aF[mi][1], bF[ni][1], acc[mi + 4][ni]);         \
        }                                                                          \
    __builtin_amdgcn_s_setprio(0);                                                 \
  }

  A_ISSUE(0)
  STAGE_B(0, 0); STAGE_B(0, 1); STAGE_B(1, 0); STAGE_B(1, 1);
  asm volatile("s_waitcnt vmcnt(8)");
  A_WRITE(0)
  asm volatile("s_waitcnt vmcnt(4) lgkmcnt(0)");
  __builtin_amdgcn_s_barrier();
  __builtin_amdgcn_sched_barrier(0);

  f16x8 bF[4][2];
  for (int t = 0; t < NT - 2; ++t) {
    const char* Acur = LDSA(t & 1);
    const char* Bcur = LDSB(t & 1);
    A_ISSUE(t + 1)
    HALF1(Acur, Bcur)
    __builtin_amdgcn_s_barrier();
    __builtin_amdgcn_sched_barrier(0);
    STAGE_B(t + 2, 0); STAGE_B(t + 2, 1);
    HALF2(Acur)
    asm volatile("s_waitcnt vmcnt(4)");
    A_WRITE(t + 1)
    asm volatile("s_waitcnt lgkmcnt(0)");
    __builtin_amdgcn_s_barrier();
    __builtin_amdgcn_sched_barrier(0);
  }
  {
    const char* Acur = LDSA((NT - 2) & 1);
    const char* Bcur = LDSB((NT - 2) & 1);
    A_ISSUE(NT - 1)
    HALF1(Acur, Bcur)
    __builtin_amdgcn_s_barrier();
    __builtin_amdgcn_sched_barrier(0);
    HALF2(Acur)
    asm volatile("s_waitcnt vmcnt(0)");
    A_WRITE(NT - 1)
    asm volatile("s_waitcnt lgkmcnt(0)");
    __builtin_amdgcn_s_barrier();
    __builtin_amdgcn_sched_barrier(0);
  }
  {
    const char* Acur = LDSA((NT - 1) & 1);
    const char* Bcur = LDSB((NT - 1) & 1);
    HALF1(Acur, Bcur)
    HALF2(Acur)
  }
#undef STAGE_B
#undef A_ISSUE
#undef A_WRITE
#undef HALF1
#undef HALF2
#undef LDSA
#undef LDSB

  stats_epilogue(lds, acc, outPart, bm0);

  const int r0 = (lane >> 4) * 4;
  const int cc = lane & 15;
#pragma unroll
  for (int mi = 0; mi < 8; ++mi) {
#pragma unroll
    for (int ni = 0; ni < 4; ++ni) {
      int r = bm0 + wm * 128 + mi * 16 + r0;
      int c = bn0 + wn * 64 + ni * 16 + cc;
#pragma unroll
      for (int j = 0; j < 4; ++j)
        O[(size_t)(r + j) * N + c] = (f16)acc[mi][ni][j];
    }
  }
}

// ======== consumer-LN fused GEMM + stats (L2/L3/L4), packed-f16 transform ========
__global__ __launch_bounds__(512, 2) void k_gemm256_ln(
    const f16* __restrict__ A, const f16* __restrict__ Bt,
    f16* __restrict__ O, const float* __restrict__ gw,
    const float* __restrict__ bw, const f32x2* __restrict__ inPart,
    f32x2* __restrict__ outPart, int N, int K) {
  __shared__ char lds[135168];  // A dbuf 2x32K @0, B dbuf 2x32K @65536, g/b 4K @131072
  const int GB = 131072;
  const int tid = threadIdx.x;
  const int lane = tid & 63;
  const int wid = tid >> 6;
  const int wm = wid >> 2;
  const int wn = wid & 3;
  const int bm0 = blockIdx.x * 256;
  const int bn0 = blockIdx.y * 256;
  const int NT = K >> 6;

  const int slin = tid * 16;
  const int lrow = slin >> 7;
  const int scol = (slin & 127) ^ ((lrow & 7) << 4);
  const char* Ab = (const char*)A;
  const char* Bb = (const char*)Bt;
  const uint32_t rs = (uint32_t)K * 2;

  const int klo = (lane >> 4) * 16;
  const int sw = (lane & 7) << 4;
  const uint32_t kx0 = (uint32_t)(klo ^ sw);
  const uint32_t kx1 = (uint32_t)((64 + klo) ^ sw);
  const uint32_t abase = (uint32_t)(wm * 128 + (lane & 15)) * 128;
  const uint32_t bbase = (uint32_t)(wn * 64 + (lane & 15)) * 128;

  const int alrow = tid >> 3;
  const uint32_t acolb = (uint32_t)(tid & 7) * 16;
  const uint32_t awcol = acolb ^ (uint32_t)((alrow & 7) << 4);
  f16 aSh[4], cSh[4];
  f16x8 ar[4];

  f32x4 acc[8][4];
#pragma unroll
  for (int i = 0; i < 8; ++i)
#pragma unroll
    for (int j = 0; j < 4; ++j) acc[i][j] = 0.0f;

#define LDSA(buf) (lds + (buf)*32768)
#define LDSB(buf) (lds + 65536 + (buf)*32768)
#define STAGE_B(t, h)                                                              \
  {                                                                                \
    const char* src = Bb + (size_t)(bn0 + (h)*128 + lrow) * rs + ((t) << 7) + scol;\
    char* dst = LDSB((t)&1) + (h)*16384 + slin;                                    \
    gload_lds16(src, dst);                                                         \
    gload_lds16(src + (size_t)64 * rs, dst + 8192);                                \
  }
#define A_ISSUE(t1)                                                               \
  {                                                                               \
    const char* base_ = Ab + (size_t)(bm0 + alrow) * rs + ((size_t)(t1) << 7) + acolb; \
    ar[0] = *(const f16x8*)(base_);                                               \
    ar[1] = *(const f16x8*)(base_ + (size_t)64 * rs);                             \
    ar[2] = *(const f16x8*)(base_ + (size_t)128 * rs);                            \
    ar[3] = *(const f16x8*)(base_ + (size_t)192 * rs);                            \
  }
// packed transform via ext-vector math: a' = relu((a*rstd + (-mu*rstd))*g + b)
#define A_WRITE(t1)                                                               \
  {                                                                               \
    uint32_t off_ = GB + (uint32_t)(t1)*128 + (uint32_t)(tid & 7) * 16;           \
    f16x8 gr = *(const f16x8*)(lds + off_);                                       \
    f16x8 br = *(const f16x8*)(lds + off_ + 2048);                                \
    char* wb_ = LDSA((t1)&1);                                                     \
    _Pragma("unroll") for (int i = 0; i < 4; ++i) {                               \
      f16x8 aS8, cS8, zz;                                                         \
      _Pragma("unroll") for (int p = 0; p < 8; ++p) {                             \
        aS8[p] = aSh[i]; cS8[p] = cSh[i]; zz[p] = (f16)0.f;                       \
      }                                                                           \
      f16x8 tt = ar[i] * aS8 + cS8;                                               \
      tt = tt * gr + br;                                                          \
      tt = __builtin_elementwise_max(tt, zz);                                     \
      *(f16x8*)(wb_ + (i >> 1) * 16384 + (alrow + (i & 1) * 64) * 128 + awcol) = tt; \
    }                                                                             \
  }

  // prologue: g/b -> LDS as f16; stats from partials; A(0) regs + B(0),B(1)
  if (tid < 256) {
    f32x4 g4 = ((const f32x4*)gw)[tid];
    f32x4 b4 = ((const f32x4*)bw)[tid];
    f16x4 gh, bh;
#pragma unroll
    for (int e = 0; e < 4; ++e) { gh[e] = (f16)g4[e]; bh[e] = (f16)b4[e]; }
    ((f16x4*)(lds + GB))[tid] = gh;
    ((f16x4*)(lds + GB + 2048))[tid] = bh;
  }
#pragma unroll
  for (int i = 0; i < 4; ++i) {
    int r = bm0 + (i >> 1) * 128 + (i & 1) * 64 + alrow;
    const f32x4* pp = (const f32x4*)(inPart + (size_t)r * 4);
    f32x4 p0 = pp[0], p1 = pp[1];
    float s = p0[0] + p0[2] + p1[0] + p1[2];
    float q = p0[1] + p0[3] + p1[1] + p1[3];
    float mu = s * (1.0f / 1024.0f);
    float var = q * (1.0f / 1024.0f) - mu * mu;
    float rstd = rsqrtf(var + LN_EPS);
    aSh[i] = (f16)rstd;
    cSh[i] = (f16)(-mu * rstd);
  }
  __builtin_amdgcn_sched_barrier(0);
  A_ISSUE(0)
  STAGE_B(0, 0); STAGE_B(0, 1); STAGE_B(1, 0); STAGE_B(1, 1);
  __builtin_amdgcn_sched_barrier(0);
  asm volatile("s_waitcnt lgkmcnt(0)");
  __builtin_amdgcn_s_barrier();               // g/b visible to all waves
  asm volatile("s_waitcnt vmcnt(8)");          // ar(0) landed
  A_WRITE(0)
  asm volatile("s_waitcnt vmcnt(4) lgkmcnt(0)");  // B(0) landed, A(0) written
  __builtin_amdgcn_s_barrier();
  __builtin_amdgcn_sched_barrier(0);

  for (int t = 0; t < NT; ++t) {
    const char* Acur = LDSA(t & 1);
    const char* Bcur = LDSB(t & 1);

    if (t + 1 < NT) { A_ISSUE(t + 1) }
    f16x8 bF[4][2];
#pragma unroll
    for (int ni = 0; ni < 4; ++ni) {
      bF[ni][0] = *(const f16x8*)(Bcur + bbase + ni * 2048 + kx0);
      bF[ni][1] = *(const f16x8*)(Bcur + bbase + ni * 2048 + kx1);
    }
    {
      f16x8 aF[4][2];
#pragma unroll
      for (int mi = 0; mi < 4; ++mi) {
        aF[mi][0] = *(const f16x8*)(Acur + abase + mi * 2048 + kx0);
        aF[mi][1] = *(const f16x8*)(Acur + abase + mi * 2048 + kx1);
      }
      __builtin_amdgcn_s_setprio(1);
#pragma unroll
      for (int mi = 0; mi < 4; ++mi)
#pragma unroll
        for (int ni = 0; ni < 4; ++ni) {
          acc[mi][ni] = mfma16(aF[mi][0], bF[ni][0], acc[mi][ni]);
          acc[mi][ni] = mfma16(aF[mi][1], bF[ni][1], acc[mi][ni]);
        }
      __builtin_amdgcn_s_setprio(0);
    }
    __builtin_amdgcn_s_barrier();
    __builtin_amdgcn_sched_barrier(0);

    if (t + 2 < NT) { STAGE_B(t + 2, 0); STAGE_B(t + 2, 1); }
    {
      f16x8 aF[4][2];
#pragma unroll
      for (int mi = 0; mi < 4; ++mi) {
        aF[mi][0] = *(const f16x8*)(Acur + abase + (mi + 4) * 2048 + kx0);
        aF[mi][1] = *(const f16x8*)(Acur + abase + (mi + 4) * 2048 + kx1);
      }
      __builtin_amdgcn_s_setprio(1);
#pragma unroll
      for (int mi = 0; mi < 4; ++mi)
#pragma unroll
        for (int ni = 0; ni < 4; ++ni) {
          acc[mi + 4][ni] = mfma16(aF[mi][0], bF[ni][0], acc[mi + 4][ni]);
          acc[mi + 4][ni] = mfma16(aF[mi][1], bF[ni][1], acc[mi + 4][ni]);
        }
      __builtin_amdgcn_s_setprio(0);
    }
    if (t + 1 < NT) {
      if (t + 2 < NT) { asm volatile("s_waitcnt vmcnt(4)"); }
      else            { asm volatile("s_waitcnt vmcnt(0)"); }
      A_WRITE(t + 1)
      asm volatile("s_waitcnt lgkmcnt(0)");
      __builtin_amdgcn_s_barrier();
      __builtin_amdgcn_sched_barrier(0);
    }
  }
#undef STAGE_B
#undef A_ISSUE
#undef A_WRITE
#undef LDSA
#undef LDSB

  stats_epilogue(lds, acc, outPart, bm0);

  const int r0 = (lane >> 4) * 4;
  const int cc = lane & 15;
#pragma unroll
  for (int mi = 0; mi < 8; ++mi) {
#pragma unroll
    for (int ni = 0; ni < 4; ++ni) {
      int r = bm0 + wm * 128 + mi * 16 + r0;
      int c = bn0 + wn * 64 + ni * 16 + cc;
#pragma unroll
      for (int j = 0; j < 4; ++j)
        O[(size_t)(r + j) * N + c] = (f16)acc[mi][ni][j];
    }
  }
}

// ======== fused LN(h4) -> G5 -> softmax, pipelined B dbuf, packed-f16 ========
__global__ __launch_bounds__(256) void k_gemm_sm(
    const f16* __restrict__ A, const f16* __restrict__ Bt,
    const float* __restrict__ gw, const float* __restrict__ bw,
    const f32x2* __restrict__ inPart, const float* __restrict__ bias,
    float* __restrict__ z, f16* __restrict__ ep, float* __restrict__ sm) {
  const int K = 1024;
  __shared__ char lds[77824];  // A 8K @0, B dbuf 2x32K @8192, g/b 4K @73728
  const int GBS = 73728;
  char* ldsA = lds;
  const int tid = threadIdx.x;
  const int lane = tid & 63;
  const int wn = tid >> 6;
  const int bm0 = blockIdx.x * 64;
  const char* Ab = (const char*)A;
  const char* Bb = (const char*)Bt;
  const uint32_t rs = (uint32_t)K * 2;
  const int cc = lane & 15;

  {
    f32x4 g4 = ((const f32x4*)gw)[tid];
    f32x4 b4 = ((const f32x4*)bw)[tid];
    f16x4 gh, bh;
#pragma unroll
    for (int e = 0; e < 4; ++e) { gh[e] = (f16)g4[e]; bh[e] = (f16)b4[e]; }
    ((f16x4*)(lds + GBS))[tid] = gh;
    ((f16x4*)(lds + GBS + 2048))[tid] = bh;
  }

  const int ar0 = tid >> 3;
  f16 aSh[2], cSh[2];
#pragma unroll
  for (int i = 0; i < 2; ++i) {
    int r = bm0 + ar0 + i * 32;
    const f32x4* pp = (const f32x4*)(inPart + (size_t)r * 4);
    f32x4 p0 = pp[0], p1 = pp[1];
    float s = p0[0] + p0[2] + p1[0] + p1[2];
    float q = p0[1] + p0[3] + p1[1] + p1[3];
    float mu = s * (1.0f / 1024.0f);
    float var = q * (1.0f / 1024.0f) - mu * mu;
    float rstd = rsqrtf(var + LN_EPS);
    aSh[i] = (f16)rstd;
    cSh[i] = (f16)(-mu * rstd);
  }
  const uint32_t acolb = (uint32_t)(tid & 7) * 16;
  const uint32_t awcol = acolb ^ (uint32_t)((ar0 & 7) << 4);

  uint32_t ra[2][4], rb[2][4];
  {
    const int sww = (lane & 7) << 4;
    const int gk = lane & 48;
#pragma unroll
    for (int kk = 0; kk < 2; ++kk) {
#pragma unroll
      for (int i = 0; i < 4; ++i) {
        uint32_t kb = (uint32_t)((kk * 64 + gk) ^ sww);
        ra[kk][i] = (uint32_t)(i * 16 + cc) * 128 + kb;
        rb[kk][i] = (uint32_t)(wn * 64 + i * 16 + cc) * 128 + kb;
      }
    }
  }

  f32x4 acc[4][4];
#pragma unroll
  for (int i = 0; i < 4; ++i)
#pragma unroll
    for (int j = 0; j < 4; ++j) acc[i][j] = 0.0f;

#define STAGE_BS(t)                                                               \
  {                                                                               \
    char* bdst = lds + 8192 + ((t)&1) * 32768;                                    \
    _Pragma("unroll") for (int i = 0; i < 8; ++i) {                               \
      int lin = i * 4096 + tid * 16;                                              \
      int row = lin >> 7;                                                         \
      int col = (lin & 127) ^ ((row & 7) << 4);                                   \
      gload_lds16(Bb + (size_t)row * rs + ((size_t)(t) << 7) + col, bdst + lin);  \
    }                                                                             \
  }

  STAGE_BS(0)
  asm volatile("s_waitcnt lgkmcnt(0)");
  __builtin_amdgcn_s_barrier();   // g/b visible
  __builtin_amdgcn_sched_barrier(0);

  for (int t = 0; t < 16; ++t) {
    const char* abase_ = Ab + (size_t)(bm0 + ar0) * rs + ((size_t)t << 7) + acolb;
    f16x8 a0 = *(const f16x8*)abase_;
    f16x8 a1 = *(const f16x8*)(abase_ + (size_t)32 * rs);
    if (t + 1 < 16) { STAGE_BS(t + 1) }
    if (t + 1 < 16) { asm volatile("s_waitcnt vmcnt(8)"); }  // drains B(t)+a0,a1
    else            { asm volatile("s_waitcnt vmcnt(0)"); }
    {
      uint32_t off_ = GBS + (uint32_t)t * 128 + (uint32_t)(tid & 7) * 16;
      f16x8 gr = *(const f16x8*)(lds + off_);
      f16x8 br = *(const f16x8*)(lds + off_ + 2048);
      f16x8 aS0, cS0, aS1, cS1, zz;
#pragma unroll
      for (int p = 0; p < 8; ++p) {
        aS0[p] = aSh[0]; cS0[p] = cSh[0];
        aS1[p] = aSh[1]; cS1[p] = cSh[1];
        zz[p] = (f16)0.f;
      }
      f16x8 t0 = a0 * aS0 + cS0;
      f16x8 t1 = a1 * aS1 + cS1;
      t0 = t0 * gr + br;
      t1 = t1 * gr + br;
      t0 = __builtin_elementwise_max(t0, zz);
      t1 = __builtin_elementwise_max(t1, zz);
      *(f16x8*)(ldsA + ar0 * 128 + awcol) = t0;
      *(f16x8*)(ldsA + (ar0 + 32) * 128 + awcol) = t1;
    }
    asm volatile("s_waitcnt lgkmcnt(0)");
    __builtin_amdgcn_s_barrier();   // ldsA written by all; B(t) landed
    __builtin_amdgcn_sched_barrier(0);
    {
      const char* Bcur = lds + 8192 + (t & 1) * 32768;
#pragma unroll
      for (int kk = 0; kk < 2; ++kk) {
        f16x8 af[4], bfv[4];
#pragma unroll
        for (int i = 0; i < 4; ++i) af[i] = *(const f16x8*)(ldsA + ra[kk][i]);
#pragma unroll
        for (int i = 0; i < 4; ++i) bfv[i] = *(const f16x8*)(Bcur + rb[kk][i]);
#pragma unroll
        for (int mi = 0; mi < 4; ++mi)
#pragma unroll
          for (int ni = 0; ni < 4; ++ni)
            acc[mi][ni] = mfma16(af[mi], bfv[ni], acc[mi][ni]);
      }
    }
    __builtin_amdgcn_s_barrier();   // all reads of ldsA / B(t) done before overwrite
    __builtin_amdgcn_sched_barrier(0);
  }
#undef STAGE_BS

  // ---- softmax epilogue over full 256-wide rows (fast-exp; keep logf for sm) ----
  __syncthreads();
  float* stm = (float*)lds;
  float* sts = (float*)(lds + 1024);
  float* rowm = (float*)(lds + 2048);
  float* rows_ = (float*)(lds + 2304);

  const int r0 = (lane >> 4) * 4;
  float bvv[4];
#pragma unroll
  for (int ni = 0; ni < 4; ++ni) bvv[ni] = bias[wn * 64 + ni * 16 + cc];

#pragma unroll
  for (int mi = 0; mi < 4; ++mi) {
#pragma unroll
    for (int j = 0; j < 4; ++j) {
      float m = -3.4e38f;
#pragma unroll
      for (int ni = 0; ni < 4; ++ni) m = fmaxf(m, acc[mi][ni][j] + bvv[ni]);
#pragma unroll
      for (int d = 1; d < 16; d <<= 1) m = fmaxf(m, __shfl_xor(m, d));
      if (cc == 0) stm[wn * 64 + mi * 16 + r0 + j] = m;
    }
  }
  __syncthreads();
  if (tid < 64) {
    float m = fmaxf(fmaxf(stm[tid], stm[64 + tid]), fmaxf(stm[128 + tid], stm[192 + tid]));
    rowm[tid] = m;
  }
  __syncthreads();
#pragma unroll
  for (int mi = 0; mi < 4; ++mi) {
#pragma unroll
    for (int j = 0; j < 4; ++j) {
      int r = mi * 16 + r0 + j;
      float m = rowm[r];
      float s = 0.f;
#pragma unroll
      for (int ni = 0; ni < 4; ++ni) s += __expf(acc[mi][ni][j] + bvv[ni] - m);
#pragma unroll
      for (int d = 1; d < 16; d <<= 1) s += __shfl_xor(s, d);
      if (cc == 0) sts[wn * 64 + r] = s;
    }
  }
  __syncthreads();
  if (tid < 64) {
    float s = sts[tid] + sts[64 + tid] + sts[128 + tid] + sts[192 + tid];
    rows_[tid] = s;
    sm[bm0 + tid] = rowm[tid] + logf(s);   // full-precision log protects p = z - sm
  }
  __syncthreads();
#pragma unroll
  for (int mi = 0; mi < 4; ++mi) {
#pragma unroll
    for (int j = 0; j < 4; ++j) {
      int r = mi * 16 + r0 + j;
      float m = rowm[r];
      float inv = 1.0f / rows_[r];
      float* zp = z + (size_t)(bm0 + r) * 256;
      f16* epp = ep + (size_t)(bm0 + r) * 256;
#pragma unroll
      for (int ni = 0; ni < 4; ++ni) {
        int c = wn * 64 + ni * 16 + cc;
        float zz = acc[mi][ni][j] + bvv[ni];
        zp[c] = zz;
        epp[c] = (f16)(__expf(zz - m) * inv);
      }
    }
  }
}

// ---------------- finalize: argmax reduce, gather q, fp32 kl from z,sm ----------------
__global__ __launch_bounds__(256) void k_final(
    const float* __restrict__ part_val, const int* __restrict__ part_idx,
    const float* __restrict__ z, const float* __restrict__ sm,
    const float* __restrict__ emb, const float* __restrict__ masks,
    float* __restrict__ q, float* __restrict__ blockloss) {
  __shared__ float ls[4];
  int lane = threadIdx.x & 63;
  int w = threadIdx.x >> 6;
  int row = blockIdx.x * 4 + w;
  float v = -3.4e38f;
  int c = 0x7fffffff;
  if (lane < 16) { v = part_val[row * 16 + lane]; c = part_idx[row * 16 + lane]; }
#pragma unroll
  for (int d = 1; d < 16; d <<= 1) {
    float ov = __shfl_xor(v, d);
    int oc = __shfl_xor(c, d);
    if (ov > v || (ov == v && oc < c)) { v = ov; c = oc; }
  }
  int code = __shfl(c, 0);
  f32x4 ev = ((const f32x4*)(emb + (size_t)code * 256))[lane];
  ((f32x4*)(q + (size_t)row * 256))[lane] = ev;
  f32x4 zv = ((const f32x4*)(z + (size_t)row * 256))[lane];
  float smr = sm[row];
  float kl = 0.f;
#pragma unroll
  for (int j = 0; j < 4; ++j) {
    float pj = zv[j] - smr;
    kl += __expf(pj) * (pj - __logf(ev[j]));
  }
#pragma unroll
  for (int d = 1; d < 64; d <<= 1) kl += __shfl_xor(kl, d);
  if (lane == 0) ls[w] = kl * masks[row];
  __syncthreads();
  if (threadIdx.x == 0) blockloss[blockIdx.x] = ls[0] + ls[1] + ls[2] + ls[3];
}

__global__ __launch_bounds__(256) void k_loss_reduce(const float* __restrict__ bl,
                                                     float* __restrict__ out) {
  __shared__ float s[256];
  float a = 0.f;
#pragma unroll
  for (int i = 0; i < 16; ++i) a += bl[threadIdx.x + i * 256];
  s[threadIdx.x] = a;
  __syncthreads();
  for (int st = 128; st > 0; st >>= 1) {
    if (threadIdx.x < st) s[threadIdx.x] += s[threadIdx.x + st];
    __syncthreads();
  }
  if (threadIdx.x == 0) out[0] = s[0] * (0.25f / 16.0f);
}

// ---------------- launch ----------------
extern "C" void kernel_launch(void* const* d_in, const int* in_sizes, int n_in,
                              void* d_out, int out_size, void* d_ws, size_t ws_size,
                              hipStream_t stream) {
  const float* x = (const float*)d_in[0];
  const float* masks = (const float*)d_in[1];
  const float* W1 = (const float*)d_in[2];
  const float* g1 = (const float*)d_in[3];
  const float* b1 = (const float*)d_in[4];
  const float* W2 = (const float*)d_in[5];
  const float* g2 = (const float*)d_in[6];
  const float* b2 = (const float*)d_in[7];
  const float* W3 = (const float*)d_in[8];
  const float* g3 = (const float*)d_in[9];
  const float* b3 = (const float*)d_in[10];
  const float* W4 = (const float*)d_in[11];
  const float* g4 = (const float*)d_in[12];
  const float* b4 = (const float*)d_in[13];
  const float* W5 = (const float*)d_in[14];
  const float* b5 = (const float*)d_in[15];
  const float* emb = (const float*)d_in[16];

  const int M = 16384;  // B*T
  char* ws = (char*)d_ws;
  f16* bufA = (f16*)(ws);                       // 32 MB ping
  f16* bufB = (f16*)(ws + (32ull << 20));       // 32 MB pong
  f16* W1t = (f16*)(ws + (64ull << 20));        // 1 MB  [1024][512]
  f16* W2t = (f16*)(ws + (65ull << 20));        // 2 MB
  f16* W3t = (f16*)(ws + (67ull << 20));        // 2 MB
  f16* W4t = (f16*)(ws + (69ull << 20));        // 2 MB
  f16* W5t = (f16*)(ws + (71ull << 20));        // 0.5 MB [256][1024]
  f16* logE = (f16*)(ws + (72ull << 20));       // 0.5 MB [1024][256]
  float* part_val = (float*)(ws + (73ull << 20));     // 1 MB
  int* part_idx = (int*)(ws + (74ull << 20));         // 1 MB
  float* blockloss = (float*)(ws + (75ull << 20));    // 16 KB
  float* sm = (float*)(ws + (76ull << 20));           // 64 KB
  f32x2* partA = (f32x2*)(ws + (77ull << 20));        // 512 KB [16384][4]
  f32x2* partB = (f32x2*)(ws + (78ull << 20));        // 512 KB
  f16* ep = (f16*)(ws + (16ull << 20));               // 8 MB, aliases bufA upper half

  float* z = (float*)d_out;                 // [16384][256]
  float* q = z + (size_t)M * 256;           // [16384][256]
  float* lossp = z + 2ull * M * 256;        // [1]

  k_prep<<<4864, 256, 0, stream>>>(W1, W1t, W2, W2t, W3, W3t, W4, W4t,
                                   W5, W5t, emb, logE);
  k_gemm256_cvt<<<dim3(64, 4), 512, 0, stream>>>(x, W1t, bufA, partA, 1024, 512);
  k_gemm256_ln<<<dim3(64, 4), 512, 0, stream>>>(bufA, W2t, bufB, g1, b1, partA, partB, 1024, 1024);
  k_gemm256_ln<<<dim3(64, 4), 512, 0, stream>>>(bufB, W3t, bufA, g2, b2, partB, partA, 1024, 1024);
  k_gemm256_ln<<<dim3(64, 4), 512, 0, stream>>>(bufA, W4t, bufB, g3, b3, partA, partB, 1024, 1024);
  k_gemm_sm<<<256, 256, 0, stream>>>(bufB, W5t, g4, b4, partB, b5, z, ep, sm);
  k_gemm256_div<<<dim3(64, 4), 512, 0, stream>>>(ep, logE, part_val, part_idx, 1024, 256);
  k_final<<<4096, 256, 0, stream>>>(part_val, part_idx, z, sm, emb, masks, q, blockloss);
  k_loss_reduce<<<1, 256, 0, stream>>>(blockloss, lossp);
}